// Round 11
// baseline (9411.488 us; speedup 1.0000x reference)
//
#include <hip/hip_runtime.h>
#include <hip/hip_bf16.h>
#include <math.h>

// ---------------------------------------------------------------------------
// SAPCABlockV5: conv1(1x1) -> center -> per-batch covariance -> eigh(top16)
//               -> softmax projection -> conv2(3x3) + BN + residual
// B=16, C=256, H=W=64, N=4096. Internal compute f32/f64. Dual dtype paths
// (bf16/f32) runtime-detected from x's bit patterns.
//
// eigh: faithful-skeleton ssyevd.
// Round-16 (this), two independent changes:
//   - k_conv2: 2 outputs/thread at columns (wl, wl+32), 8-row tile (grid ht
//     16->8). Keeps the PROVEN R5 schedule recipe exactly: cc-outer,
//     dd-unrolled, unpadded wt[16][8][9], scalar broadcast wt reads. The 9
//     wt reads per (cc,dd) are shared across both outputs -> -17% instrs
//     per output. Column split +32 keeps y-reads at 2 lanes/bank (free),
//     unlike adjacent columns (4-way). Per-acc FMA order (dd asc, k asc)
//     unchanged -> bit-identical. THIRD conv2 attempt: if this regresses,
//     conv2 is closed.
//   - k_scy = fused k_score + k_y: thread-local column of g is read fully,
//     z computed in registers (identical FP sequence), softmax, then y
//     written over g. No races (each thread owns column n). z buffer gone.
//   Everything else byte-frozen from the 7482us Round-15 state:
//   sytd2 512-thread (1024 regressed, do not raise), backtf 512,
//   conv1/cmat/center/leaf/msolve/mvec unchanged.
//   absmax must stay EXACTLY 0.015625.
// ---------------------------------------------------------------------------

typedef __hip_bfloat16 bf16;

#define NB 16
#define NC 256
#define NSP 4096
#define LAPACK_EPS32 5.9604644775390625e-08

#define PHB_I0 80
#define PHB_M  176   // 256 - PHB_I0; 176*176*4B = 123904B LDS

__device__ __forceinline__ float b2f(bf16 v){ return __bfloat162float(v); }
__device__ __forceinline__ double safelog(double x){
  double a = fabs(x);
  if (!(a > 0.0) || !isfinite(a)) a = 1e-300;
  return log(a);
}

// 256-thread block-wide sum (used by unchanged kernels).
__device__ __forceinline__ float blk_reduce_sum(float s, float* red, int tid){
  red[tid] = s; __syncthreads();
  if (tid < 128) red[tid] += red[tid+128];
  __syncthreads();
  if (tid < 64){
    float x = red[tid] + red[tid+64];
    #pragma unroll
    for (int o = 32; o > 0; o >>= 1) x += __shfl_down(x, o);
    if (tid == 0) red[0] = x;
  }
  __syncthreads();
  return red[0];
}

// 512-thread block-wide sum.
__device__ __forceinline__ float blk_reduce_sum512(float s, float* red, int tid){
  red[tid] = s; __syncthreads();
  if (tid < 256) red[tid] += red[tid+256];
  __syncthreads();
  if (tid < 128) red[tid] += red[tid+128];
  __syncthreads();
  if (tid < 64){
    float x = red[tid] + red[tid+64];
    #pragma unroll
    for (int o = 32; o > 0; o >>= 1) x += __shfl_down(x, o);
    if (tid == 0) red[0] = x;
  }
  __syncthreads();
  return red[0];
}

// ------------------------- dtype probe --------------------------------------
__global__ __launch_bounds__(256) void k_detect(const unsigned short* __restrict__ xr,
                                                int* __restrict__ flags){
  __shared__ int red[256];
  int tid = threadIdx.x;
  int cnt = 0;
  for (int i = tid; i < 4096; i += 256){
    unsigned int u = xr[i];
    unsigned int e = (u >> 7) & 0xFF;
    if (e >= 134) ++cnt;
  }
  red[tid] = cnt; __syncthreads();
  for (int o=128;o>0;o>>=1){ if(tid<o) red[tid]+=red[tid+o]; __syncthreads(); }
  if (tid==0) flags[0] = (red[0] > 50) ? 1 : 0;   // 1 = inputs are f32
}

// ------------------------- conv1 (1x1) : g = W1 @ x --------------------------
// ws transposed to [d][ci] + float4 uniform reads (bit-exact since R13).
__global__ __launch_bounds__(256) void k_conv1(const void* __restrict__ xv_,
                                               const void* __restrict__ w1v,
                                               const int* __restrict__ flags,
                                               float* __restrict__ g){
  __shared__ __attribute__((aligned(16))) float ws[256][16];   // [d][ci]
  int nt = blockIdx.x, ct = blockIdx.y, b = blockIdx.z;
  int tid = threadIdx.x;
  int c0 = ct*16;
  int isf = flags[0];
  if (isf){
    const float* w1 = (const float*)w1v;
    for (int i = tid; i < 16*256; i += 256)
      ws[i&255][i>>8] = w1[(size_t)(c0 + (i>>8))*256 + (i&255)];
  } else {
    const bf16* w1 = (const bf16*)w1v;
    for (int i = tid; i < 16*256; i += 256)
      ws[i&255][i>>8] = b2f(w1[(size_t)(c0 + (i>>8))*256 + (i&255)]);
  }
  __syncthreads();
  int n = nt*256 + tid;
  float acc[16];
  #pragma unroll
  for (int i=0;i<16;++i) acc[i]=0.f;
  if (isf){
    const float* xp = (const float*)xv_ + (size_t)b*NC*NSP + n;
    for (int d=0; d<256; ++d){
      float xv = xp[(size_t)d*NSP];
      float4 wa=*(const float4*)&ws[d][0];
      float4 wb=*(const float4*)&ws[d][4];
      float4 wc=*(const float4*)&ws[d][8];
      float4 wd=*(const float4*)&ws[d][12];
      acc[0] =fmaf(wa.x,xv,acc[0]);  acc[1] =fmaf(wa.y,xv,acc[1]);
      acc[2] =fmaf(wa.z,xv,acc[2]);  acc[3] =fmaf(wa.w,xv,acc[3]);
      acc[4] =fmaf(wb.x,xv,acc[4]);  acc[5] =fmaf(wb.y,xv,acc[5]);
      acc[6] =fmaf(wb.z,xv,acc[6]);  acc[7] =fmaf(wb.w,xv,acc[7]);
      acc[8] =fmaf(wc.x,xv,acc[8]);  acc[9] =fmaf(wc.y,xv,acc[9]);
      acc[10]=fmaf(wc.z,xv,acc[10]); acc[11]=fmaf(wc.w,xv,acc[11]);
      acc[12]=fmaf(wd.x,xv,acc[12]); acc[13]=fmaf(wd.y,xv,acc[13]);
      acc[14]=fmaf(wd.z,xv,acc[14]); acc[15]=fmaf(wd.w,xv,acc[15]);
    }
  } else {
    const bf16* xp = (const bf16*)xv_ + (size_t)b*NC*NSP + n;
    for (int d=0; d<256; ++d){
      float xv = b2f(xp[(size_t)d*NSP]);
      float4 wa=*(const float4*)&ws[d][0];
      float4 wb=*(const float4*)&ws[d][4];
      float4 wc=*(const float4*)&ws[d][8];
      float4 wd=*(const float4*)&ws[d][12];
      acc[0] =fmaf(wa.x,xv,acc[0]);  acc[1] =fmaf(wa.y,xv,acc[1]);
      acc[2] =fmaf(wa.z,xv,acc[2]);  acc[3] =fmaf(wa.w,xv,acc[3]);
      acc[4] =fmaf(wb.x,xv,acc[4]);  acc[5] =fmaf(wb.y,xv,acc[5]);
      acc[6] =fmaf(wb.z,xv,acc[6]);  acc[7] =fmaf(wb.w,xv,acc[7]);
      acc[8] =fmaf(wc.x,xv,acc[8]);  acc[9] =fmaf(wc.y,xv,acc[9]);
      acc[10]=fmaf(wc.z,xv,acc[10]); acc[11]=fmaf(wc.w,xv,acc[11]);
      acc[12]=fmaf(wd.x,xv,acc[12]); acc[13]=fmaf(wd.y,xv,acc[13]);
      acc[14]=fmaf(wd.z,xv,acc[14]); acc[15]=fmaf(wd.w,xv,acc[15]);
    }
  }
  float* gp = g + ((size_t)b*NC + c0)*NSP + n;
  #pragma unroll
  for (int i=0;i<16;++i) gp[(size_t)i*NSP] = acc[i];
}

// ------------------------- center over spatial -------------------------------
__global__ __launch_bounds__(256) void k_center(float* __restrict__ g){
  int bc = blockIdx.x;
  float* p = g + (size_t)bc*NSP;
  int tid = threadIdx.x;
  __shared__ float red[256];
  float s = 0.f;
  for (int i=tid;i<NSP;i+=256) s += p[i];
  red[tid]=s; __syncthreads();
  for (int o=128;o>0;o>>=1){ if(tid<o) red[tid]+=red[tid+o]; __syncthreads(); }
  float mean = red[0] * (1.0f/4096.0f);
  for (int i=tid;i<NSP;i+=256) p[i] -= mean;
}

// ------------------------- cmat = g g^T / 16 ---------------------------------
__global__ __launch_bounds__(256) void k_cmat(const float* __restrict__ g,
                                              float* __restrict__ A){
  __shared__ float t1[32][65];
  __shared__ float t2[32][65];
  int bx = blockIdx.x, by = blockIdx.y, b = blockIdx.z;
  int tid = threadIdx.x;
  int tx = tid & 31, ty = tid >> 5;
  const float* gb = g + (size_t)b*NC*NSP;
  float acc[4] = {0.f,0.f,0.f,0.f};
  for (int ch=0; ch<64; ++ch){
    int n0 = ch*64;
    for (int idx=tid; idx<2048; idx+=256){
      int r = idx>>6, cc = idx&63;
      t1[r][cc] = gb[(size_t)(by*32 + r)*NSP + n0 + cc];
      t2[r][cc] = gb[(size_t)(bx*32 + r)*NSP + n0 + cc];
    }
    __syncthreads();
    for (int kk=0; kk<64; ++kk){
      float v2 = t2[tx][kk];
      #pragma unroll
      for (int jj=0;jj<4;++jj) acc[jj] = fmaf(t1[ty+8*jj][kk], v2, acc[jj]);
    }
    __syncthreads();
  }
  #pragma unroll
  for (int jj=0;jj<4;++jj){
    int row = by*32 + ty + 8*jj, col = bx*32 + tx;
    A[((size_t)b*NC + row)*NC + col] = acc[jj]*(1.0f/16.0f);
  }
}

// ------------------------- sytd2 (LAPACK 'L'), transposed addressing ---------
// 512 threads (PROVEN best): rid=tid&255 -> row i+1+rid, half=tid>>8 ->
// column half. 1024-thread quarter split regressed (R14); do not raise.
__global__ __launch_bounds__(512,1) void k_sytd2(float* __restrict__ Ag,
                                                 float* __restrict__ e_g,
                                                 float* __restrict__ tau_g,
                                                 float* __restrict__ d_g){
  int b = blockIdx.x, tid = threadIdx.x;
  int rid = tid & 255, half = tid >> 8;
  float* A = Ag + (size_t)b*65536;
  __shared__ float Asub[PHB_M*PHB_M];
  __shared__ float v[256], wv[256];
  __shared__ float red[512];
  __shared__ float accbuf[512];

  // ---------------- phase A: steps 0..PHB_I0-1 on global A -----------------
  for (int i=0;i<PHB_I0;++i){
    float alpha = A[(size_t)i*256+(i+1)];
    float s=0.f;
    { int r=i+2+tid; if (r<256){ float a=A[(size_t)i*256+r]; s=a*a; } }
    float xnorm2 = blk_reduce_sum512(s, red, tid);
    float tau=0.f, scale=0.f, beta=alpha;
    if (xnorm2 > 0.f){
      float r_ = sqrtf(alpha*alpha + xnorm2);
      beta = (alpha >= 0.f) ? -r_ : r_;       // -SIGN(r, alpha)
      tau = (beta - alpha)/beta;
      scale = 1.0f/(alpha - beta);
    }
    if (tid==0){ e_g[b*256+i] = beta; tau_g[b*256+i] = tau; }
    if (tau != 0.f){
      { int r=i+1+tid;
        if (r<256){
          float val = (r==i+1)?1.0f : A[(size_t)i*256+r]*scale;
          A[(size_t)i*256+r] = val;  v[r] = val;
        }
      }
      __syncthreads();
      int r = i+1+rid;
      bool rv = (r < 256);
      int cmid = (i+1+256) >> 1;
      int cstart = (half==0)? (i+1) : cmid;
      int cend   = (half==0)? cmid  : 256;
      // ---- matvec half: acc = sum_{c in [cstart,cend)} A[c,r]*v[c] --------
      {
        float acc=0.f;
        if (rv){
          const float* Ar = A + r;
          int nfull = (cend-cstart) >> 4;
          float b0[16], b1[16];
          if (nfull>0){
            #pragma unroll
            for (int u=0;u<16;++u) b0[u] = Ar[(size_t)(cstart+u)*256];
          }
          int t=0;
          for (; t+2<=nfull; t+=2){
            int cB = cstart+(t+1)*16;
            #pragma unroll
            for (int u=0;u<16;++u) b1[u] = Ar[(size_t)(cB+u)*256];
            int cA = cstart+t*16;
            #pragma unroll
            for (int u=0;u<16;++u) acc = fmaf(b0[u], v[cA+u], acc);
            if (t+2 < nfull){
              int cC = cstart+(t+2)*16;
              #pragma unroll
              for (int u=0;u<16;++u) b0[u] = Ar[(size_t)(cC+u)*256];
            }
            #pragma unroll
            for (int u=0;u<16;++u) acc = fmaf(b1[u], v[cB+u], acc);
          }
          if (t<nfull){
            int cA = cstart+t*16;
            #pragma unroll
            for (int u=0;u<16;++u) acc = fmaf(b0[u], v[cA+u], acc);
            ++t;
          }
          for (int c2=cstart+nfull*16; c2<cend; ++c2)
            acc = fmaf(Ar[(size_t)c2*256], v[c2], acc);
        }
        accbuf[half*256+rid] = acc;
      }
      __syncthreads();
      if (half==0 && rv) wv[r] = tau*(accbuf[rid] + accbuf[256+rid]);
      __syncthreads();
      float sd = (half==0 && rv)? v[r]*wv[r] : 0.f;
      float dotv = blk_reduce_sum512(sd, red, tid);
      float a2 = -0.5f*tau*dotv;
      if (half==0 && rv) wv[r] += a2*v[r];
      __syncthreads();
      // ---- rank-2 half: A[c,r] -= v[r]*wv[c] + wv[r]*v[c], c in half ------
      if (rv){
        float vr=v[r], wr=wv[r];
        float* Arw = A + r;
        int nfull = (cend-cstart) >> 4;
        float b0[16], b1[16];
        if (nfull>0){
          #pragma unroll
          for (int u=0;u<16;++u) b0[u] = Arw[(size_t)(cstart+u)*256];
        }
        int t=0;
        for (; t+2<=nfull; t+=2){
          int cB = cstart+(t+1)*16;
          #pragma unroll
          for (int u=0;u<16;++u) b1[u] = Arw[(size_t)(cB+u)*256];
          int cA = cstart+t*16;
          #pragma unroll
          for (int u=0;u<16;++u) b0[u] -= vr*wv[cA+u] + wr*v[cA+u];
          #pragma unroll
          for (int u=0;u<16;++u) Arw[(size_t)(cA+u)*256] = b0[u];
          if (t+2 < nfull){
            int cC = cstart+(t+2)*16;
            #pragma unroll
            for (int u=0;u<16;++u) b0[u] = Arw[(size_t)(cC+u)*256];
          }
          #pragma unroll
          for (int u=0;u<16;++u) b1[u] -= vr*wv[cB+u] + wr*v[cB+u];
          #pragma unroll
          for (int u=0;u<16;++u) Arw[(size_t)(cB+u)*256] = b1[u];
        }
        if (t<nfull){
          int cA = cstart+t*16;
          #pragma unroll
          for (int u=0;u<16;++u) b0[u] -= vr*wv[cA+u] + wr*v[cA+u];
          #pragma unroll
          for (int u=0;u<16;++u) Arw[(size_t)(cA+u)*256] = b0[u];
          ++t;
        }
        for (int c2=cstart+nfull*16; c2<cend; ++c2)
          Arw[(size_t)c2*256] -= vr*wv[c2] + wr*v[c2];
      }
      __syncthreads();
    }
    __syncthreads();
  }

  // ------------- copy trailing submatrix [PHB_I0..255]^2 to LDS ------------
  for (int idx=tid; idx<PHB_M*PHB_M; idx+=512){
    int cc = idx / PHB_M, rr = idx - cc*PHB_M;
    Asub[idx] = A[(size_t)(PHB_I0+cc)*256 + (PHB_I0+rr)];
  }
  __syncthreads();

  // ---------------- phase B: steps PHB_I0..254 in LDS ----------------------
  for (int i=PHB_I0;i<255;++i){
    int cb = (i - PHB_I0)*PHB_M;
    float alpha = Asub[cb + (i+1-PHB_I0)];
    float s=0.f;
    { int r=i+2+tid; if (r<256){ float a=Asub[cb + (r-PHB_I0)]; s=a*a; } }
    float xnorm2 = blk_reduce_sum512(s, red, tid);
    float tau=0.f, scale=0.f, beta=alpha;
    if (xnorm2 > 0.f){
      float r_ = sqrtf(alpha*alpha + xnorm2);
      beta = (alpha >= 0.f) ? -r_ : r_;
      tau = (beta - alpha)/beta;
      scale = 1.0f/(alpha - beta);
    }
    if (tid==0){ e_g[b*256+i] = beta; tau_g[b*256+i] = tau; }
    if (tau != 0.f){
      { int r=i+1+tid;
        if (r<256){
          float val = (r==i+1)?1.0f : Asub[cb+(r-PHB_I0)]*scale;
          Asub[cb+(r-PHB_I0)] = val;
          A[(size_t)i*256+r] = val;   // write-through: k_backtf reads this column
          v[r] = val;
        }
      }
      __syncthreads();
      int r = i+1+rid;
      bool rv = (r < 256);
      int ro = r - PHB_I0;
      int cmid = (i+1+256) >> 1;
      int cstart = (half==0)? (i+1) : cmid;
      int cend   = (half==0)? cmid  : 256;
      {
        float acc=0.f;
        if (rv){
          int nfull = (cend-cstart) >> 4;
          for (int t=0;t<nfull;++t){
            int cA = cstart + t*16;
            float av[16];
            #pragma unroll
            for (int u=0;u<16;++u) av[u] = Asub[(cA+u-PHB_I0)*PHB_M + ro];
            #pragma unroll
            for (int u=0;u<16;++u) acc = fmaf(av[u], v[cA+u], acc);
          }
          for (int c2=cstart+nfull*16;c2<cend;++c2)
            acc = fmaf(Asub[(c2-PHB_I0)*PHB_M+ro], v[c2], acc);
        }
        accbuf[half*256+rid] = acc;
      }
      __syncthreads();
      if (half==0 && rv) wv[r] = tau*(accbuf[rid] + accbuf[256+rid]);
      __syncthreads();
      float sd = (half==0 && rv)? v[r]*wv[r] : 0.f;
      float dotv = blk_reduce_sum512(sd, red, tid);
      float a2 = -0.5f*tau*dotv;
      if (half==0 && rv) wv[r] += a2*v[r];
      __syncthreads();
      if (rv){
        float vr=v[r], wr=wv[r];
        int nfull = (cend-cstart) >> 4;
        for (int t=0;t<nfull;++t){
          int cA=cstart+t*16;
          float av[16];
          #pragma unroll
          for (int u=0;u<16;++u) av[u] = Asub[(cA+u-PHB_I0)*PHB_M+ro];
          #pragma unroll
          for (int u=0;u<16;++u) av[u] -= vr*wv[cA+u] + wr*v[cA+u];
          #pragma unroll
          for (int u=0;u<16;++u) Asub[(cA+u-PHB_I0)*PHB_M+ro] = av[u];
        }
        for (int c2=cstart+nfull*16;c2<cend;++c2)
          Asub[(c2-PHB_I0)*PHB_M+ro] -= vr*wv[c2] + wr*v[c2];
      }
      __syncthreads();
    }
    __syncthreads();
  }
  if (tid < 256){
    int r = tid;
    float dv = (r >= PHB_I0)? Asub[(r-PHB_I0)*PHB_M + (r-PHB_I0)] : A[(size_t)r*256+r];
    d_g[b*256+r] = dv;
  }
}

// ------------------- leaves: lockstep wave-parallel Jacobi -------------------
__global__ __launch_bounds__(256) void k_leaf(const float* __restrict__ d_g,
                                              const float* __restrict__ e_g,
                                              float* __restrict__ Qg,
                                              double* __restrict__ Dw_g,
                                              double* __restrict__ emod_g){
  int b = blockIdx.x, tid = threadIdx.x;
  float* Q = Qg + (size_t)b*65536;
  double* Dw = Dw_g + (size_t)b*256;
  __shared__ double As[16*257];
  __shared__ float  Vt[16*257];
  __shared__ double dms[256];
  __shared__ double emod[256];
  __shared__ float redf[256];

  float dv = d_g[b*256+tid];
  float ev = (tid<255)? e_g[b*256+tid] : 0.f;
  redf[tid] = fmaxf(fabsf(dv), fabsf(ev)); __syncthreads();
  for(int o=128;o>0;o>>=1){ if(tid<o) redf[tid]=fmaxf(redf[tid],redf[tid+o]); __syncthreads(); }
  double sigma = (double)redf[0];
  if (!(sigma > 0.0)) sigma = 1.0;
  double dmod = (double)dv;
  if ((tid & 15)==15 && tid<255) dmod -= fabs((double)e_g[b*256+tid]);
  if ((tid & 15)==0  && tid>0)   dmod -= fabs((double)e_g[b*256+tid-1]);
  dmod /= sigma;
  double em = (tid<255)? ((double)ev)/sigma : 0.0;
  dms[tid] = dmod;  emod[tid] = em;
  emod_g[b*256+tid] = em;
  __syncthreads();

  int l16 = tid & ~15, j = tid & 15;
  for (int r=0;r<16;++r){
    double av = 0.0;
    if (r==j)        av = dms[l16+j];
    else if (r==j-1) av = emod[l16+j-1];
    else if (r==j+1) av = emod[l16+j];
    As[r*257+tid] = av;
    Vt[r*257+tid] = (r==j)? 1.f : 0.f;
  }
  __syncthreads();

  for (int sweep=0; sweep<14; ++sweep){
    for (int p=0;p<15;++p){
      for (int q=p+1;q<16;++q){
        double app = As[p*257 + l16+p];
        double aqq = As[q*257 + l16+q];
        double apq = As[p*257 + l16+q];
        bool rot = (fabs(apq) > 1e-18);
        double c, s;
        if (rot){
          double theta = (aqq - app)/(2.0*apq);
          double t = 1.0/(fabs(theta)+sqrt(1.0+theta*theta));
          if (theta < 0.0) t = -t;
          c = 1.0/sqrt(1.0+t*t); s = t*c;
        } else { c = 1.0; s = 0.0; }
        double apj = As[p*257 + tid];
        double aqj = As[q*257 + tid];
        double npj = c*apj - s*aqj;
        double nqj = s*apj + c*aqj;
        if (rot && j==p){ npj = c*c*app - 2.0*c*s*apq + s*s*aqq; nqj = 0.0; }
        if (rot && j==q){ npj = 0.0; nqj = s*s*app + 2.0*c*s*apq + c*c*aqq; }
        As[p*257 + tid] = npj;
        As[q*257 + tid] = nqj;
        As[j*257 + l16+p] = npj;
        As[j*257 + l16+q] = nqj;
        float vp = Vt[p*257 + tid], vq = Vt[q*257 + tid];
        Vt[p*257 + tid] = (float)(c*(double)vp - s*(double)vq);
        Vt[q*257 + tid] = (float)(s*(double)vp + c*(double)vq);
      }
    }
  }
  __syncthreads();
  double myval = As[j*257 + l16+j];
  int rank = 0;
  for (int k=0;k<16;++k){
    double vk = As[k*257 + l16+k];
    if (vk < myval || (vk==myval && k<j)) ++rank;
  }
  Dw[l16+rank] = myval;
  for (int r=0;r<16;++r)
    Q[(size_t)(l16+r)*256 + (l16+rank)] = Vt[j*257 + l16+r];
}

// ---------------- merge solve (slaed2 + secular), one block per merge --------
struct DCMerge {
  double z_[256], dsv[256], ds2[256], zs2[256];
  double dl_[256], zl_[256], taus[256], ztil[256], normk[256], evo[256];
  double rotcs[256][2];
  int    cs2[256], colx[256], non_[256], defl_[256], anch[256], osrc[256], otyp[256];
  int    roti[256][2];
};

// Global state layout, slot = b*8 + mrg, each array stride 256 per slot.
__global__ __launch_bounds__(256) void k_msolve(int lev,
                                                const double* __restrict__ emod_g,
                                                float* __restrict__ Qsrc,   // rotated in place
                                                double* __restrict__ Dw_g,
                                                double* __restrict__ Sdl,
                                                double* __restrict__ Sztil,
                                                double* __restrict__ Staus,
                                                double* __restrict__ Snk,
                                                int* __restrict__ Scolx,
                                                int* __restrict__ Sanch,
                                                int* __restrict__ Sotyp,
                                                int* __restrict__ Sosrc,
                                                int* __restrict__ SK){
  int mrg = blockIdx.x, b = blockIdx.y, tid = threadIdx.x;
  float* Q  = Qsrc + (size_t)b*65536;
  double* Dw = Dw_g + (size_t)b*256;
  int slot = b*8 + mrg;
  __shared__ DCMerge mg;
  __shared__ int bci[4];

  int ssz = 16<<lev, nm = ssz<<1;
  int base = mrg*nm;
  double rho0 = emod_g[b*256 + base+ssz-1];
  if (tid < nm){
    float zf = (tid < ssz) ? Q[(size_t)(base+ssz-1)*256 + base + tid]
                           : Q[(size_t)(base+ssz)*256   + base + tid];
    double zz = (double)zf;
    if (rho0 < 0.0 && tid >= ssz) zz = -zz;
    mg.z_[tid] = zz * 0.70710678118654752440;
    mg.dsv[tid] = Dw[base+tid];
  }
  __syncthreads();
  double rho = fabs(2.0*rho0);
  if (tid==0){
    int i1=0, i2=ssz, o=0;
    while (i1<ssz || i2<nm){
      bool take1;
      if (i1>=ssz) take1=false; else if (i2>=nm) take1=true;
      else take1 = (mg.dsv[i1] <= mg.dsv[i2]);
      int src = take1? i1++ : i2++;
      mg.ds2[o]=mg.dsv[src]; mg.zs2[o]=mg.z_[src]; mg.cs2[o]=src; ++o;
    }
  }
  __syncthreads();
  mg.taus[tid] = (tid<nm)? fabs(mg.zs2[tid]) : 0.0; __syncthreads();
  for(int o2=128;o2>0;o2>>=1){ if(tid<o2) mg.taus[tid]=fmax(mg.taus[tid],mg.taus[tid+o2]); __syncthreads(); }
  double zmax = mg.taus[0]; __syncthreads();
  mg.taus[tid] = (tid<nm)? fabs(mg.ds2[tid]) : 0.0; __syncthreads();
  for(int o2=128;o2>0;o2>>=1){ if(tid<o2) mg.taus[tid]=fmax(mg.taus[tid],mg.taus[tid+o2]); __syncthreads(); }
  double dmax = mg.taus[0]; __syncthreads();
  double tol = 8.0*LAPACK_EPS32*fmax(dmax, zmax);
  if (tid==0){
    int K=0, nd=0, nrot=0, pj=-1;
    for (int j=0;j<nm;++j){
      if (rho*fabs(mg.zs2[j]) <= tol){ mg.defl_[nd++]=j; continue; }
      if (pj>=0){
        double sg=mg.zs2[pj], cg=mg.zs2[j];
        double tg=mg.ds2[j]-mg.ds2[pj];
        double taug=sqrt(cg*cg+sg*sg);
        double cn, sn;
        if (taug > 0.0){ cn=cg/taug; sn=-sg/taug; } else { cn=1.0; sn=0.0; }
        if (fabs(tg*cn*sn) <= tol){
          mg.zs2[j]=taug; mg.zs2[pj]=0.0;
          mg.roti[nrot][0]=mg.cs2[pj]; mg.roti[nrot][1]=mg.cs2[j];
          mg.rotcs[nrot][0]=cn; mg.rotcs[nrot][1]=sn; ++nrot;
          double t2 = mg.ds2[pj]*cn*cn + mg.ds2[j]*sn*sn;
          mg.ds2[j] = mg.ds2[pj]*sn*sn + mg.ds2[j]*cn*cn;
          mg.ds2[pj] = t2;
          mg.defl_[nd++]=pj;
          pj=j;
        } else { mg.non_[K++]=pj; pj=j; }
      } else pj=j;
    }
    if (pj>=0) mg.non_[K++]=pj;
    bci[0]=K; bci[1]=nd; bci[2]=nrot;
  }
  __syncthreads();
  int K=bci[0], nd=bci[1], nrot=bci[2];
  // Givens rotations on src Q columns (in order)
  for (int r2=0;r2<nrot;++r2){
    int ca = base + mg.roti[r2][0], cb2 = base + mg.roti[r2][1];
    double cn = mg.rotcs[r2][0], sn = mg.rotcs[r2][1];
    if (tid < nm){
      int row = base+tid;
      float xv = Q[(size_t)row*256+ca], yv = Q[(size_t)row*256+cb2];
      Q[(size_t)row*256+ca]  = (float)(cn*(double)xv + sn*(double)yv);
      Q[(size_t)row*256+cb2] = (float)(cn*(double)yv - sn*(double)xv);
    }
    __syncthreads();
  }
  if (tid<K){
    mg.dl_[tid]=mg.ds2[mg.non_[tid]];
    mg.zl_[tid]=mg.zs2[mg.non_[tid]];
    mg.colx[tid]=mg.cs2[mg.non_[tid]];
  }
  __syncthreads();
  mg.taus[tid] = (tid<K)? mg.zl_[tid]*mg.zl_[tid] : 0.0; __syncthreads();
  for(int o2=128;o2>0;o2>>=1){ if(tid<o2) mg.taus[tid]+=mg.taus[tid+o2]; __syncthreads(); }
  double zsum2 = mg.taus[0]; __syncthreads();
  if (tid<K){
    int j=tid;
    double left=mg.dl_[j];
    double right=(j<K-1)? mg.dl_[j+1] : (mg.dl_[K-1] + rho*zsum2);
    double mid=0.5*(left+right);
    double fm=1.0;
    for (int i3=0;i3<K;++i3){
      double del=mg.dl_[i3]-mid;
      fm += rho*mg.zl_[i3]*mg.zl_[i3]/del;
    }
    int a; double lo, hi;
    if (j==K-1){
      a=K-1;
      if (fm<=0.0){ lo=mid-left; hi=right-left; } else { lo=0.0; hi=mid-left; }
    } else if (fm<=0.0){ a=j+1; lo=mid-mg.dl_[j+1]; hi=0.0; }
    else { a=j; lo=0.0; hi=mid-left; }
    double da2=mg.dl_[a];
    double t;
    if (hi > lo){
      t=0.5*(lo+hi);
    } else {
      t = (a==j)? 1e-300 : -1e-300;
      lo = fmin(lo, t); hi = fmax(hi, t);
    }
    for (int it=0; it<100; ++it){
      double gg=1.0, dg=0.0;
      for (int i3=0;i3<K;++i3){
        double del=(mg.dl_[i3]-da2)-t;
        double q=mg.zl_[i3]/del;
        gg += rho*mg.zl_[i3]*q;
        dg += rho*q*q;
      }
      if (gg<0.0) lo=t; else hi=t;
      double tn = t - gg/dg;
      if (!isfinite(tn) || !(tn>lo && tn<hi)) tn=0.5*(lo+hi);
      if (tn == 0.0) tn = (t!=0.0)? t*0.5 : ((a==j)?1e-300:-1e-300);
      double dstep=fabs(tn-t);
      t=tn;
      if (dstep <= 1e-15*(fabs(t)+1e-30)) break;
      if ((hi-lo) <= 1e-15*(fabs(da2)+fabs(t)+1e-30)) break;
    }
    if (t == 0.0 || !isfinite(t)) t = (a==j)? 1e-300 : -1e-300;
    mg.taus[j]=t; mg.anch[j]=a;
  }
  __syncthreads();
  if (tid<K){
    int i3=tid; double acc=0.0; double di=mg.dl_[i3];
    for (int j=0;j<K;++j){
      double lmd = (mg.dl_[mg.anch[j]] - di) + mg.taus[j];
      acc += safelog(lmd);
      if (j!=i3) acc -= safelog(mg.dl_[j]-di);
    }
    double mag = exp(0.5*acc);
    if (!isfinite(mag)) mag = 0.0;
    mg.ztil[i3] = (mg.zl_[i3] >= 0.0)? mag : -mag;
  }
  __syncthreads();
  if (tid<K){
    int j=tid; double da2=mg.dl_[mg.anch[j]]; double tj=mg.taus[j];
    double nr=0.0;
    for (int i3=0;i3<K;++i3){
      double del=(mg.dl_[i3]-da2)-tj;
      if (del == 0.0) del = (tj>=0.0)? -1e-300 : 1e-300;
      double sv=mg.ztil[i3]/del;
      nr += sv*sv;
    }
    if (!(nr > 0.0) || !isfinite(nr)) nr = 1.0;
    mg.normk[j]=sqrt(nr);
  }
  __syncthreads();
  // output ordering
  if (tid==0){
    for (int a2=1;a2<nd;++a2){
      int key=mg.defl_[a2]; double kv=mg.ds2[key]; int b2=a2-1;
      while (b2>=0 && mg.ds2[mg.defl_[b2]] > kv){ mg.defl_[b2+1]=mg.defl_[b2]; --b2; }
      mg.defl_[b2+1]=key;
    }
    int i1=0,i2=0,o=0;
    while (i1<K || i2<nd){
      double v1 = (i1<K)? (mg.dl_[mg.anch[i1]]+mg.taus[i1]) : 0.0;
      double v2 = (i2<nd)? mg.ds2[mg.defl_[i2]] : 0.0;
      bool take1;
      if (i1>=K) take1=false; else if (i2>=nd) take1=true; else take1 = (v1 <= v2);
      if (take1){ mg.otyp[o]=0; mg.osrc[o]=i1; mg.evo[o]=v1; ++i1; }
      else { mg.otyp[o]=1; mg.osrc[o]=mg.cs2[mg.defl_[i2]]; mg.evo[o]=v2; ++i2; }
      ++o;
    }
  }
  __syncthreads();
  if (tid<nm) Dw[base+tid]=mg.evo[tid];
  // write state
  size_t so = (size_t)slot*256;
  if (tid<K){
    Sdl[so+tid]=mg.dl_[tid]; Sztil[so+tid]=mg.ztil[tid];
    Staus[so+tid]=mg.taus[tid]; Snk[so+tid]=mg.normk[tid];
    Scolx[so+tid]=mg.colx[tid]; Sanch[so+tid]=mg.anch[tid];
  }
  if (tid<nm){ Sotyp[so+tid]=mg.otyp[tid]; Sosrc[so+tid]=mg.osrc[tid]; }
  if (tid==0) SK[slot]=K;
}

// ---------------- merge assemble: Qdst[:,p] = Qsrc_sub @ svf  ----------------
// grid: (nm/16 col-tiles, nmerge, 16 batches); block 256.
__global__ __launch_bounds__(256) void k_mvec(int lev,
                                              const float* __restrict__ Qsrc_g,
                                              float* __restrict__ Qdst_g,
                                              const double* __restrict__ Sdl,
                                              const double* __restrict__ Sztil,
                                              const double* __restrict__ Staus,
                                              const double* __restrict__ Snk,
                                              const int* __restrict__ Scolx,
                                              const int* __restrict__ Sanch,
                                              const int* __restrict__ Sotyp,
                                              const int* __restrict__ Sosrc,
                                              const int* __restrict__ SK){
  int t = blockIdx.x, mrg = blockIdx.y, b = blockIdx.z, tid = threadIdx.x;
  const float* Q = Qsrc_g + (size_t)b*65536;
  float* Qd = Qdst_g + (size_t)b*65536;
  int slot = b*8 + mrg;
  size_t so = (size_t)slot*256;
  int ssz = 16<<lev, nm = ssz<<1;
  int base = mrg*nm;
  int p0 = t*16;
  int K = SK[slot];

  __shared__ float svf[256*16];      // [i3][c], stride 16: compute idx==tid -> conflict-free
  __shared__ double cda[16], ctj[16];
  __shared__ float cnk[16];
  __shared__ int ctyp[16], csrc[16];

  if (tid < 16){
    int p = p0 + tid;
    int typ = Sotyp[so+p], src = Sosrc[so+p];
    ctyp[tid]=typ; csrc[tid]=src;
    if (typ==0){
      int j = src;
      cda[tid] = Sdl[so + Sanch[so+j] - 0 + 0];    // placeholder; fixed below
    }
  }
  __syncthreads();
  // fix cda/ctj/cnk properly (need anch lookup)
  if (tid < 16){
    int p = p0 + tid;
    if (ctyp[tid]==0){
      int j = csrc[tid];
      int a = Sanch[so+j];
      cda[tid] = Sdl[so+a];
      ctj[tid] = Staus[so+j];
      cnk[tid] = (float)Snk[so+j];
    } else { cda[tid]=0.0; ctj[tid]=1.0; cnk[tid]=1.f; }
  }
  __syncthreads();
  // build svf tile
  for (int idx = tid; idx < K*16; idx += 256){
    int i3 = idx >> 4, c = idx & 15;
    float sv = 0.f;
    if (ctyp[c]==0){
      double del = (Sdl[so+i3] - cda[c]) - ctj[c];
      if (del == 0.0) del = (ctj[c]>=0.0)? -1e-300 : 1e-300;
      sv = (float)( Sztil[so+i3]/del / (double)cnk[c] );
      if (!isfinite(sv)) sv = 0.f;
    }
    svf[i3*16 + c] = sv;
  }
  __syncthreads();

  // rows: one thread per row (nm <= 256)
  if (tid < nm){
    int row = base + tid;
    const float* Qr = Q + (size_t)row*256 + base;
    float acc[16];
    #pragma unroll
    for (int c=0;c<16;++c) acc[c]=0.f;
    for (int i3=0;i3<K;++i3){
      float qv = Qr[Scolx[so+i3]];
      #pragma unroll
      for (int c=0;c<16;++c) acc[c] = fmaf(qv, svf[i3*16+c], acc[c]);
    }
    #pragma unroll
    for (int c=0;c<16;++c){
      float v = acc[c];
      if (ctyp[c]==1) v = Qr[csrc[c]];
      if (!isfinite(v)) v = 0.f;
      Qd[(size_t)row*256 + base + p0 + c] = v;
    }
  }
}

// --------------- back-transform: U16 = H_1...H_255 * Vtri[:,240:256] ---------
// 512 threads (measured win in R14/R15): 32 row-groups x 8 rows.
__global__ __launch_bounds__(512,1) void k_backtf(const float* __restrict__ Ag,
                                                  const float* __restrict__ tau_g,
                                                  const float* __restrict__ Qg,
                                                  float* __restrict__ w16g){
  int b=blockIdx.x, tid=threadIdx.x;
  const float* A=Ag+(size_t)b*65536;
  const float* Q=Qg+(size_t)b*65536;
  __shared__ float U[256][17];
  __shared__ float pd[32][17];
  __shared__ float dk[16];
  int k=tid&15, rg=tid>>4;   // rg in 0..31
  for (int r=rg;r<256;r+=32) U[r][k]=Q[(size_t)r*256+240+k];
  __syncthreads();
  for (int i=254;i>=0;--i){
    float tau=tau_g[b*256+i];
    if (tau!=0.f){
      int r0 = i+1+rg;
      float ar[8];
      #pragma unroll
      for (int u=0;u<8;++u){
        int r = r0 + u*32;
        ar[u] = (r<256)? A[(size_t)i*256+r] : 0.f;
      }
      float uv[8];
      #pragma unroll
      for (int u=0;u<8;++u){
        int r = r0 + u*32;
        uv[u] = (r<256)? U[r][k] : 0.f;
      }
      float s=0.f;
      #pragma unroll
      for (int u=0;u<8;++u){
        int r = r0 + u*32;
        if (r<256) s += ar[u]*uv[u];
      }
      pd[rg][k]=s;
      __syncthreads();
      if (tid<16){
        float acc=0.f;
        #pragma unroll
        for (int gg=0; gg<32; ++gg) acc+=pd[gg][tid];
        dk[tid]=tau*acc;
      }
      __syncthreads();
      float dkk = dk[k];
      #pragma unroll
      for (int u=0;u<8;++u){
        int r = r0 + u*32;
        if (r<256) U[r][k] -= dkk*ar[u];
      }
      __syncthreads();
    }
  }
  for (int c2=rg;c2<256;c2+=32){
    float uv = U[c2][k];
    if (!isfinite(uv)) uv = 0.f;
    w16g[((size_t)b*16+k)*256+c2]=uv;
  }
}

// ---------------- fused scores + softmax + y (replaces k_score/k_y) ----------
// Each thread owns column n of g: reads all 256 channels (score, identical
// FP sequence to old k_score), softmaxes, then writes y over the same column
// (identical FP sequence to old k_y). z never materialized. No cross-thread
// sharing of g columns -> race-free in-place.
__global__ __launch_bounds__(256) void k_scy(float* __restrict__ g,
                                             const float* __restrict__ w16){
  __shared__ __attribute__((aligned(16))) float ws[256][16];   // [c2][k2]
  int nt=blockIdx.x, b=blockIdx.y, tid=threadIdx.x;
  for (int i=tid;i<4096;i+=256) ws[i&255][i>>8]=w16[(size_t)b*4096+i];
  __syncthreads();
  int n=nt*256+tid;
  float* gp=g+(size_t)b*NC*NSP+n;
  float acc[16];
  #pragma unroll
  for(int k2=0;k2<16;++k2) acc[k2]=0.f;
  for (int c2=0;c2<256;++c2){
    float gv=gp[(size_t)c2*NSP];
    float4 wa=*(const float4*)&ws[c2][0];
    float4 wb=*(const float4*)&ws[c2][4];
    float4 wc=*(const float4*)&ws[c2][8];
    float4 wd=*(const float4*)&ws[c2][12];
    acc[0] =fmaf(wa.x,gv,acc[0]);  acc[1] =fmaf(wa.y,gv,acc[1]);
    acc[2] =fmaf(wa.z,gv,acc[2]);  acc[3] =fmaf(wa.w,gv,acc[3]);
    acc[4] =fmaf(wb.x,gv,acc[4]);  acc[5] =fmaf(wb.y,gv,acc[5]);
    acc[6] =fmaf(wb.z,gv,acc[6]);  acc[7] =fmaf(wb.w,gv,acc[7]);
    acc[8] =fmaf(wc.x,gv,acc[8]);  acc[9] =fmaf(wc.y,gv,acc[9]);
    acc[10]=fmaf(wc.z,gv,acc[10]); acc[11]=fmaf(wc.w,gv,acc[11]);
    acc[12]=fmaf(wd.x,gv,acc[12]); acc[13]=fmaf(wd.y,gv,acc[13]);
    acc[14]=fmaf(wd.z,gv,acc[14]); acc[15]=fmaf(wd.w,gv,acc[15]);
  }
  float mx=-1e30f;
  #pragma unroll
  for(int k2=0;k2<16;++k2){ acc[k2]*=3.0f; mx=fmaxf(mx,acc[k2]); }
  float sum=0.f;
  #pragma unroll
  for(int k2=0;k2<16;++k2){ acc[k2]=expf(acc[k2]-mx); sum+=acc[k2]; }
  float inv=1.0f/sum;
  #pragma unroll
  for(int k2=0;k2<16;++k2) acc[k2]*=inv;     // z values, identical to old path
  for (int c2=0;c2<256;++c2){
    float4 wa=*(const float4*)&ws[c2][0];
    float4 wb=*(const float4*)&ws[c2][4];
    float4 wc=*(const float4*)&ws[c2][8];
    float4 wd=*(const float4*)&ws[c2][12];
    float a=0.f;
    a=fmaf(wa.x,acc[0],a);  a=fmaf(wa.y,acc[1],a);
    a=fmaf(wa.z,acc[2],a);  a=fmaf(wa.w,acc[3],a);
    a=fmaf(wb.x,acc[4],a);  a=fmaf(wb.y,acc[5],a);
    a=fmaf(wb.z,acc[6],a);  a=fmaf(wb.w,acc[7],a);
    a=fmaf(wc.x,acc[8],a);  a=fmaf(wc.y,acc[9],a);
    a=fmaf(wc.z,acc[10],a); a=fmaf(wc.w,acc[11],a);
    a=fmaf(wd.x,acc[12],a); a=fmaf(wd.y,acc[13],a);
    a=fmaf(wd.z,acc[14],a); a=fmaf(wd.w,acc[15],a);
    gp[(size_t)c2*NSP]=a;
  }
}

// ------------------------- conv2(3x3) + BN + residual ------------------------
// Round-16: 2 outputs/thread at columns (wl, wl+32); 8-row tile, grid ht=8.
// Schedule recipe identical to the proven R5 form: cc-outer, dd-unrolled,
// unpadded wt[16][8][9], scalar broadcast wt reads (shared across both
// outputs). Per-acc FMA order (dd asc, k asc) unchanged -> bit-identical.
__global__ __launch_bounds__(256) void k_conv2(const float* __restrict__ y,
                                               const void* __restrict__ w2v,
                                               const void* __restrict__ xv_,
                                               const void* __restrict__ gmv,
                                               const void* __restrict__ btv,
                                               const void* __restrict__ muv,
                                               const void* __restrict__ vrv,
                                               const int* __restrict__ flags,
                                               void* __restrict__ outv){
  __shared__ float yt[8][10][66];
  __shared__ float wt[16][8][9];
  int ht=blockIdx.x, ct=blockIdx.y, b=blockIdx.z, tid=threadIdx.x;
  int wl=tid&31, hl=tid>>5;          // 32 cols x 8 rows
  int h=ht*8+hl;
  int c0=ct*16;
  int isf = flags[0];
  float accA[16], accB[16];
  #pragma unroll
  for(int i=0;i<16;++i){ accA[i]=0.f; accB[i]=0.f; }
  const float* yb = y + (size_t)b*NC*NSP;
  for (int d0=0; d0<256; d0+=8){
    for (int idx=tid; idx<8*10*64; idx+=256){
      int dd=idx/640; int rem=idx-dd*640; int rr=rem>>6; int cc2=rem&63;
      int hg=ht*8-1+rr;
      float v = (hg>=0 && hg<64)? yb[(size_t)(d0+dd)*NSP + hg*64 + cc2] : 0.f;
      yt[dd][rr][cc2+1]=v;
    }
    if (tid<80){ int dd=tid/10, rr=tid-dd*10; yt[dd][rr][0]=0.f; yt[dd][rr][65]=0.f; }
    if (isf){
      const float* w2 = (const float*)w2v;
      for (int idx=tid; idx<16*8*9; idx+=256){
        int cc=idx/72; int rem=idx-cc*72; int dd=rem/9; int kk=rem-dd*9;
        wt[cc][dd][kk]=w2[ ((size_t)(c0+cc)*256 + d0+dd)*9 + kk ];
      }
    } else {
      const bf16* w2 = (const bf16*)w2v;
      for (int idx=tid; idx<16*8*9; idx+=256){
        int cc=idx/72; int rem=idx-cc*72; int dd=rem/9; int kk=rem-dd*9;
        wt[cc][dd][kk]=b2f(w2[ ((size_t)(c0+cc)*256 + d0+dd)*9 + kk ]);
      }
    }
    __syncthreads();
    for (int cc=0; cc<16; ++cc){
      float a=accA[cc], c=accB[cc];
      #pragma unroll
      for (int dd=0; dd<8; ++dd){
        const float* wp=wt[cc][dd];
        // position A: output col wl   -> padded cols wl..wl+2
        a = fmaf(wp[0], yt[dd][hl+0][wl+0], a);
        a = fmaf(wp[1], yt[dd][hl+0][wl+1], a);
        a = fmaf(wp[2], yt[dd][hl+0][wl+2], a);
        a = fmaf(wp[3], yt[dd][hl+1][wl+0], a);
        a = fmaf(wp[4], yt[dd][hl+1][wl+1], a);
        a = fmaf(wp[5], yt[dd][hl+1][wl+2], a);
        a = fmaf(wp[6], yt[dd][hl+2][wl+0], a);
        a = fmaf(wp[7], yt[dd][hl+2][wl+1], a);
        a = fmaf(wp[8], yt[dd][hl+2][wl+2], a);
        // position B: output col wl+32 -> padded cols wl+32..wl+34
        c = fmaf(wp[0], yt[dd][hl+0][wl+32], c);
        c = fmaf(wp[1], yt[dd][hl+0][wl+33], c);
        c = fmaf(wp[2], yt[dd][hl+0][wl+34], c);
        c = fmaf(wp[3], yt[dd][hl+1][wl+32], c);
        c = fmaf(wp[4], yt[dd][hl+1][wl+33], c);
        c = fmaf(wp[5], yt[dd][hl+1][wl+34], c);
        c = fmaf(wp[6], yt[dd][hl+2][wl+32], c);
        c = fmaf(wp[7], yt[dd][hl+2][wl+33], c);
        c = fmaf(wp[8], yt[dd][hl+2][wl+34], c);
      }
      accA[cc]=a; accB[cc]=c;
    }
    __syncthreads();
  }
  size_t n0=(size_t)h*64+wl;
  size_t n1=n0+32;
  for (int cc=0;cc<16;++cc){
    int c=c0+cc;
    float gmf, btf, muf, vrf, xv0, xv1;
    size_t oi0 = ((size_t)b*NC+c)*NSP + n0;
    size_t oi1 = ((size_t)b*NC+c)*NSP + n1;
    if (isf){
      gmf=((const float*)gmv)[c]; btf=((const float*)btv)[c];
      muf=((const float*)muv)[c]; vrf=((const float*)vrv)[c];
      xv0=((const float*)xv_)[oi0]; xv1=((const float*)xv_)[oi1];
    } else {
      gmf=b2f(((const bf16*)gmv)[c]); btf=b2f(((const bf16*)btv)[c]);
      muf=b2f(((const bf16*)muv)[c]); vrf=b2f(((const bf16*)vrv)[c]);
      xv0=b2f(((const bf16*)xv_)[oi0]); xv1=b2f(((const bf16*)xv_)[oi1]);
    }
    float inv = gmf * rsqrtf(vrf + 1e-5f);
    float shift = btf - muf*inv;
    float v0 = xv0 + accA[cc]*inv + shift;
    float v1 = xv1 + accB[cc]*inv + shift;
    if (isf){ ((float*)outv)[oi0] = v0; ((float*)outv)[oi1] = v1; }
    else    { ((bf16*)outv)[oi0] = __float2bfloat16(v0);
              ((bf16*)outv)[oi1] = __float2bfloat16(v1); }
  }
}

// ---------------------------------------------------------------------------
extern "C" void kernel_launch(void* const* d_in, const int* in_sizes, int n_in,
                              void* d_out, int out_size, void* d_ws, size_t ws_size,
                              hipStream_t stream) {
  const void* x   = d_in[0];
  const void* w1  = d_in[1];
  // d_in[2] = conv1_b: constant over spatial -> cancelled by centering; unused.
  const void* w2  = d_in[3];
  const void* gmm = d_in[4];
  const void* bet = d_in[5];
  const void* mu  = d_in[6];
  const void* var = d_in[7];

  float* g    = (float*)d_ws;                      // 16*256*4096 (later reused as y)
  float* A    = g   + (size_t)NB*NC*NSP;
  float* Qa   = A   + (size_t)NB*NC*NC;
  float* Qb   = Qa  + (size_t)NB*NC*NC;
  float* w16  = Qb  + (size_t)NB*NC*NC;
  float* zb   = w16 + (size_t)NB*16*NC;            // unused since R16 fusion
  float* e_g  = zb  + (size_t)NB*16*NSP;
  float* tau_g= e_g + (size_t)NB*NC;
  float* d_g  = tau_g + (size_t)NB*NC;
  double* Dw  = (double*)(d_g + (size_t)NB*NC);
  double* emod_g = Dw + (size_t)NB*NC;
  double* Sdl   = emod_g + (size_t)NB*NC;
  double* Sztil = Sdl   + (size_t)128*256;
  double* Staus = Sztil + (size_t)128*256;
  double* Snk   = Staus + (size_t)128*256;
  int* Scolx = (int*)(Snk + (size_t)128*256);
  int* Sanch = Scolx + (size_t)128*256;
  int* Sotyp = Sanch + (size_t)128*256;
  int* Sosrc = Sotyp + (size_t)128*256;
  int* SK    = Sosrc + (size_t)128*256;
  int* flags = SK + 256;
  size_t needed = (size_t)((char*)(flags + 16) - (char*)d_ws);
  if (ws_size < needed) return;

  hipMemsetAsync(Qa, 0, (size_t)NB*NC*NC*2*sizeof(float), stream);  // Qa+Qb contiguous
  k_detect<<<dim3(1),256,0,stream>>>((const unsigned short*)x, flags);
  k_conv1 <<<dim3(16,16,16),256,0,stream>>>(x, w1, flags, g);
  k_center<<<dim3(NB*NC),256,0,stream>>>(g);
  k_cmat  <<<dim3(8,8,16),256,0,stream>>>(g, A);
  k_sytd2 <<<dim3(16),512,0,stream>>>(A, e_g, tau_g, d_g);
  k_leaf  <<<dim3(16),256,0,stream>>>(d_g, e_g, Qa, Dw, emod_g);
  // lev0: Qa -> Qb
  k_msolve<<<dim3(8,16),256,0,stream>>>(0, emod_g, Qa, Dw, Sdl,Sztil,Staus,Snk,Scolx,Sanch,Sotyp,Sosrc,SK);
  k_mvec  <<<dim3(2,8,16),256,0,stream>>>(0, Qa, Qb, Sdl,Sztil,Staus,Snk,Scolx,Sanch,Sotyp,Sosrc,SK);
  // lev1: Qb -> Qa
  k_msolve<<<dim3(4,16),256,0,stream>>>(1, emod_g, Qb, Dw, Sdl,Sztil,Staus,Snk,Scolx,Sanch,Sotyp,Sosrc,SK);
  k_mvec  <<<dim3(4,4,16),256,0,stream>>>(1, Qb, Qa, Sdl,Sztil,Staus,Snk,Scolx,Sanch,Sotyp,Sosrc,SK);
  // lev2: Qa -> Qb
  k_msolve<<<dim3(2,16),256,0,stream>>>(2, emod_g, Qa, Dw, Sdl,Sztil,Staus,Snk,Scolx,Sanch,Sotyp,Sosrc,SK);
  k_mvec  <<<dim3(8,2,16),256,0,stream>>>(2, Qa, Qb, Sdl,Sztil,Staus,Snk,Scolx,Sanch,Sotyp,Sosrc,SK);
  // lev3: Qb -> Qa
  k_msolve<<<dim3(1,16),256,0,stream>>>(3, emod_g, Qb, Dw, Sdl,Sztil,Staus,Snk,Scolx,Sanch,Sotyp,Sosrc,SK);
  k_mvec  <<<dim3(16,1,16),256,0,stream>>>(3, Qb, Qa, Sdl,Sztil,Staus,Snk,Scolx,Sanch,Sotyp,Sosrc,SK);
  k_backtf<<<dim3(16),512,0,stream>>>(A, tau_g, Qa, w16);
  k_scy   <<<dim3(16,16),256,0,stream>>>(g, w16);       // fused score+softmax+y (in-place)
  k_conv2 <<<dim3(8,16,16),256,0,stream>>>(g, w2, x, gmm, bet, mu, var, flags, d_out);
}

// Round 12
// 7441.708 us; speedup vs baseline: 1.2647x; 1.2647x over previous
//
#include <hip/hip_runtime.h>
#include <hip/hip_bf16.h>
#include <math.h>

// ---------------------------------------------------------------------------
// SAPCABlockV5: conv1(1x1) -> center -> per-batch covariance -> eigh(top16)
//               -> softmax projection -> conv2(3x3) + BN + residual
// B=16, C=256, H=W=64, N=4096. Internal compute f32/f64. Dual dtype paths
// (bf16/f32) runtime-detected from x's bit patterns.
//
// eigh: faithful-skeleton ssyevd.
// Round-17: k_conv2 is CLOSED. Three restructure attempts all regressed:
//   R11 pad+full-unroll (bank conflicts 19x, VGPR 132), R12 dd-outer
//   (VGPR capped 28, exposed lgkmcnt), R16 2-outputs/thread (VGPR 132,
//   occupancy 44%->12%, 3813us). Any increase in per-thread live state on
//   the dd-unrolled schedule tips the allocator past the occupancy cliff.
//   k_conv2 below is the Round-5 text verbatim (1832us), grid ht=16.
//   k_scy fusion kept (accounting: R16 Dtotal = Dconv2 -> scy neutral+,
//   bit-exact). Everything else byte-frozen from the 7482us state.
//   absmax must stay EXACTLY 0.015625.
// ---------------------------------------------------------------------------

typedef __hip_bfloat16 bf16;

#define NB 16
#define NC 256
#define NSP 4096
#define LAPACK_EPS32 5.9604644775390625e-08

#define PHB_I0 80
#define PHB_M  176   // 256 - PHB_I0; 176*176*4B = 123904B LDS

__device__ __forceinline__ float b2f(bf16 v){ return __bfloat162float(v); }
__device__ __forceinline__ double safelog(double x){
  double a = fabs(x);
  if (!(a > 0.0) || !isfinite(a)) a = 1e-300;
  return log(a);
}

// 256-thread block-wide sum (used by unchanged kernels).
__device__ __forceinline__ float blk_reduce_sum(float s, float* red, int tid){
  red[tid] = s; __syncthreads();
  if (tid < 128) red[tid] += red[tid+128];
  __syncthreads();
  if (tid < 64){
    float x = red[tid] + red[tid+64];
    #pragma unroll
    for (int o = 32; o > 0; o >>= 1) x += __shfl_down(x, o);
    if (tid == 0) red[0] = x;
  }
  __syncthreads();
  return red[0];
}

// 512-thread block-wide sum.
__device__ __forceinline__ float blk_reduce_sum512(float s, float* red, int tid){
  red[tid] = s; __syncthreads();
  if (tid < 256) red[tid] += red[tid+256];
  __syncthreads();
  if (tid < 128) red[tid] += red[tid+128];
  __syncthreads();
  if (tid < 64){
    float x = red[tid] + red[tid+64];
    #pragma unroll
    for (int o = 32; o > 0; o >>= 1) x += __shfl_down(x, o);
    if (tid == 0) red[0] = x;
  }
  __syncthreads();
  return red[0];
}

// ------------------------- dtype probe --------------------------------------
__global__ __launch_bounds__(256) void k_detect(const unsigned short* __restrict__ xr,
                                                int* __restrict__ flags){
  __shared__ int red[256];
  int tid = threadIdx.x;
  int cnt = 0;
  for (int i = tid; i < 4096; i += 256){
    unsigned int u = xr[i];
    unsigned int e = (u >> 7) & 0xFF;
    if (e >= 134) ++cnt;
  }
  red[tid] = cnt; __syncthreads();
  for (int o=128;o>0;o>>=1){ if(tid<o) red[tid]+=red[tid+o]; __syncthreads(); }
  if (tid==0) flags[0] = (red[0] > 50) ? 1 : 0;   // 1 = inputs are f32
}

// ------------------------- conv1 (1x1) : g = W1 @ x --------------------------
// ws transposed to [d][ci] + float4 uniform reads (bit-exact since R13).
__global__ __launch_bounds__(256) void k_conv1(const void* __restrict__ xv_,
                                               const void* __restrict__ w1v,
                                               const int* __restrict__ flags,
                                               float* __restrict__ g){
  __shared__ __attribute__((aligned(16))) float ws[256][16];   // [d][ci]
  int nt = blockIdx.x, ct = blockIdx.y, b = blockIdx.z;
  int tid = threadIdx.x;
  int c0 = ct*16;
  int isf = flags[0];
  if (isf){
    const float* w1 = (const float*)w1v;
    for (int i = tid; i < 16*256; i += 256)
      ws[i&255][i>>8] = w1[(size_t)(c0 + (i>>8))*256 + (i&255)];
  } else {
    const bf16* w1 = (const bf16*)w1v;
    for (int i = tid; i < 16*256; i += 256)
      ws[i&255][i>>8] = b2f(w1[(size_t)(c0 + (i>>8))*256 + (i&255)]);
  }
  __syncthreads();
  int n = nt*256 + tid;
  float acc[16];
  #pragma unroll
  for (int i=0;i<16;++i) acc[i]=0.f;
  if (isf){
    const float* xp = (const float*)xv_ + (size_t)b*NC*NSP + n;
    for (int d=0; d<256; ++d){
      float xv = xp[(size_t)d*NSP];
      float4 wa=*(const float4*)&ws[d][0];
      float4 wb=*(const float4*)&ws[d][4];
      float4 wc=*(const float4*)&ws[d][8];
      float4 wd=*(const float4*)&ws[d][12];
      acc[0] =fmaf(wa.x,xv,acc[0]);  acc[1] =fmaf(wa.y,xv,acc[1]);
      acc[2] =fmaf(wa.z,xv,acc[2]);  acc[3] =fmaf(wa.w,xv,acc[3]);
      acc[4] =fmaf(wb.x,xv,acc[4]);  acc[5] =fmaf(wb.y,xv,acc[5]);
      acc[6] =fmaf(wb.z,xv,acc[6]);  acc[7] =fmaf(wb.w,xv,acc[7]);
      acc[8] =fmaf(wc.x,xv,acc[8]);  acc[9] =fmaf(wc.y,xv,acc[9]);
      acc[10]=fmaf(wc.z,xv,acc[10]); acc[11]=fmaf(wc.w,xv,acc[11]);
      acc[12]=fmaf(wd.x,xv,acc[12]); acc[13]=fmaf(wd.y,xv,acc[13]);
      acc[14]=fmaf(wd.z,xv,acc[14]); acc[15]=fmaf(wd.w,xv,acc[15]);
    }
  } else {
    const bf16* xp = (const bf16*)xv_ + (size_t)b*NC*NSP + n;
    for (int d=0; d<256; ++d){
      float xv = b2f(xp[(size_t)d*NSP]);
      float4 wa=*(const float4*)&ws[d][0];
      float4 wb=*(const float4*)&ws[d][4];
      float4 wc=*(const float4*)&ws[d][8];
      float4 wd=*(const float4*)&ws[d][12];
      acc[0] =fmaf(wa.x,xv,acc[0]);  acc[1] =fmaf(wa.y,xv,acc[1]);
      acc[2] =fmaf(wa.z,xv,acc[2]);  acc[3] =fmaf(wa.w,xv,acc[3]);
      acc[4] =fmaf(wb.x,xv,acc[4]);  acc[5] =fmaf(wb.y,xv,acc[5]);
      acc[6] =fmaf(wb.z,xv,acc[6]);  acc[7] =fmaf(wb.w,xv,acc[7]);
      acc[8] =fmaf(wc.x,xv,acc[8]);  acc[9] =fmaf(wc.y,xv,acc[9]);
      acc[10]=fmaf(wc.z,xv,acc[10]); acc[11]=fmaf(wc.w,xv,acc[11]);
      acc[12]=fmaf(wd.x,xv,acc[12]); acc[13]=fmaf(wd.y,xv,acc[13]);
      acc[14]=fmaf(wd.z,xv,acc[14]); acc[15]=fmaf(wd.w,xv,acc[15]);
    }
  }
  float* gp = g + ((size_t)b*NC + c0)*NSP + n;
  #pragma unroll
  for (int i=0;i<16;++i) gp[(size_t)i*NSP] = acc[i];
}

// ------------------------- center over spatial -------------------------------
__global__ __launch_bounds__(256) void k_center(float* __restrict__ g){
  int bc = blockIdx.x;
  float* p = g + (size_t)bc*NSP;
  int tid = threadIdx.x;
  __shared__ float red[256];
  float s = 0.f;
  for (int i=tid;i<NSP;i+=256) s += p[i];
  red[tid]=s; __syncthreads();
  for (int o=128;o>0;o>>=1){ if(tid<o) red[tid]+=red[tid+o]; __syncthreads(); }
  float mean = red[0] * (1.0f/4096.0f);
  for (int i=tid;i<NSP;i+=256) p[i] -= mean;
}

// ------------------------- cmat = g g^T / 16 ---------------------------------
__global__ __launch_bounds__(256) void k_cmat(const float* __restrict__ g,
                                              float* __restrict__ A){
  __shared__ float t1[32][65];
  __shared__ float t2[32][65];
  int bx = blockIdx.x, by = blockIdx.y, b = blockIdx.z;
  int tid = threadIdx.x;
  int tx = tid & 31, ty = tid >> 5;
  const float* gb = g + (size_t)b*NC*NSP;
  float acc[4] = {0.f,0.f,0.f,0.f};
  for (int ch=0; ch<64; ++ch){
    int n0 = ch*64;
    for (int idx=tid; idx<2048; idx+=256){
      int r = idx>>6, cc = idx&63;
      t1[r][cc] = gb[(size_t)(by*32 + r)*NSP + n0 + cc];
      t2[r][cc] = gb[(size_t)(bx*32 + r)*NSP + n0 + cc];
    }
    __syncthreads();
    for (int kk=0; kk<64; ++kk){
      float v2 = t2[tx][kk];
      #pragma unroll
      for (int jj=0;jj<4;++jj) acc[jj] = fmaf(t1[ty+8*jj][kk], v2, acc[jj]);
    }
    __syncthreads();
  }
  #pragma unroll
  for (int jj=0;jj<4;++jj){
    int row = by*32 + ty + 8*jj, col = bx*32 + tx;
    A[((size_t)b*NC + row)*NC + col] = acc[jj]*(1.0f/16.0f);
  }
}

// ------------------------- sytd2 (LAPACK 'L'), transposed addressing ---------
// 512 threads (PROVEN best): rid=tid&255 -> row i+1+rid, half=tid>>8 ->
// column half. 1024-thread quarter split regressed (R14); do not raise.
__global__ __launch_bounds__(512,1) void k_sytd2(float* __restrict__ Ag,
                                                 float* __restrict__ e_g,
                                                 float* __restrict__ tau_g,
                                                 float* __restrict__ d_g){
  int b = blockIdx.x, tid = threadIdx.x;
  int rid = tid & 255, half = tid >> 8;
  float* A = Ag + (size_t)b*65536;
  __shared__ float Asub[PHB_M*PHB_M];
  __shared__ float v[256], wv[256];
  __shared__ float red[512];
  __shared__ float accbuf[512];

  // ---------------- phase A: steps 0..PHB_I0-1 on global A -----------------
  for (int i=0;i<PHB_I0;++i){
    float alpha = A[(size_t)i*256+(i+1)];
    float s=0.f;
    { int r=i+2+tid; if (r<256){ float a=A[(size_t)i*256+r]; s=a*a; } }
    float xnorm2 = blk_reduce_sum512(s, red, tid);
    float tau=0.f, scale=0.f, beta=alpha;
    if (xnorm2 > 0.f){
      float r_ = sqrtf(alpha*alpha + xnorm2);
      beta = (alpha >= 0.f) ? -r_ : r_;       // -SIGN(r, alpha)
      tau = (beta - alpha)/beta;
      scale = 1.0f/(alpha - beta);
    }
    if (tid==0){ e_g[b*256+i] = beta; tau_g[b*256+i] = tau; }
    if (tau != 0.f){
      { int r=i+1+tid;
        if (r<256){
          float val = (r==i+1)?1.0f : A[(size_t)i*256+r]*scale;
          A[(size_t)i*256+r] = val;  v[r] = val;
        }
      }
      __syncthreads();
      int r = i+1+rid;
      bool rv = (r < 256);
      int cmid = (i+1+256) >> 1;
      int cstart = (half==0)? (i+1) : cmid;
      int cend   = (half==0)? cmid  : 256;
      // ---- matvec half: acc = sum_{c in [cstart,cend)} A[c,r]*v[c] --------
      {
        float acc=0.f;
        if (rv){
          const float* Ar = A + r;
          int nfull = (cend-cstart) >> 4;
          float b0[16], b1[16];
          if (nfull>0){
            #pragma unroll
            for (int u=0;u<16;++u) b0[u] = Ar[(size_t)(cstart+u)*256];
          }
          int t=0;
          for (; t+2<=nfull; t+=2){
            int cB = cstart+(t+1)*16;
            #pragma unroll
            for (int u=0;u<16;++u) b1[u] = Ar[(size_t)(cB+u)*256];
            int cA = cstart+t*16;
            #pragma unroll
            for (int u=0;u<16;++u) acc = fmaf(b0[u], v[cA+u], acc);
            if (t+2 < nfull){
              int cC = cstart+(t+2)*16;
              #pragma unroll
              for (int u=0;u<16;++u) b0[u] = Ar[(size_t)(cC+u)*256];
            }
            #pragma unroll
            for (int u=0;u<16;++u) acc = fmaf(b1[u], v[cB+u], acc);
          }
          if (t<nfull){
            int cA = cstart+t*16;
            #pragma unroll
            for (int u=0;u<16;++u) acc = fmaf(b0[u], v[cA+u], acc);
            ++t;
          }
          for (int c2=cstart+nfull*16; c2<cend; ++c2)
            acc = fmaf(Ar[(size_t)c2*256], v[c2], acc);
        }
        accbuf[half*256+rid] = acc;
      }
      __syncthreads();
      if (half==0 && rv) wv[r] = tau*(accbuf[rid] + accbuf[256+rid]);
      __syncthreads();
      float sd = (half==0 && rv)? v[r]*wv[r] : 0.f;
      float dotv = blk_reduce_sum512(sd, red, tid);
      float a2 = -0.5f*tau*dotv;
      if (half==0 && rv) wv[r] += a2*v[r];
      __syncthreads();
      // ---- rank-2 half: A[c,r] -= v[r]*wv[c] + wv[r]*v[c], c in half ------
      if (rv){
        float vr=v[r], wr=wv[r];
        float* Arw = A + r;
        int nfull = (cend-cstart) >> 4;
        float b0[16], b1[16];
        if (nfull>0){
          #pragma unroll
          for (int u=0;u<16;++u) b0[u] = Arw[(size_t)(cstart+u)*256];
        }
        int t=0;
        for (; t+2<=nfull; t+=2){
          int cB = cstart+(t+1)*16;
          #pragma unroll
          for (int u=0;u<16;++u) b1[u] = Arw[(size_t)(cB+u)*256];
          int cA = cstart+t*16;
          #pragma unroll
          for (int u=0;u<16;++u) b0[u] -= vr*wv[cA+u] + wr*v[cA+u];
          #pragma unroll
          for (int u=0;u<16;++u) Arw[(size_t)(cA+u)*256] = b0[u];
          if (t+2 < nfull){
            int cC = cstart+(t+2)*16;
            #pragma unroll
            for (int u=0;u<16;++u) b0[u] = Arw[(size_t)(cC+u)*256];
          }
          #pragma unroll
          for (int u=0;u<16;++u) b1[u] -= vr*wv[cB+u] + wr*v[cB+u];
          #pragma unroll
          for (int u=0;u<16;++u) Arw[(size_t)(cB+u)*256] = b1[u];
        }
        if (t<nfull){
          int cA = cstart+t*16;
          #pragma unroll
          for (int u=0;u<16;++u) b0[u] -= vr*wv[cA+u] + wr*v[cA+u];
          #pragma unroll
          for (int u=0;u<16;++u) Arw[(size_t)(cA+u)*256] = b0[u];
          ++t;
        }
        for (int c2=cstart+nfull*16; c2<cend; ++c2)
          Arw[(size_t)c2*256] -= vr*wv[c2] + wr*v[c2];
      }
      __syncthreads();
    }
    __syncthreads();
  }

  // ------------- copy trailing submatrix [PHB_I0..255]^2 to LDS ------------
  for (int idx=tid; idx<PHB_M*PHB_M; idx+=512){
    int cc = idx / PHB_M, rr = idx - cc*PHB_M;
    Asub[idx] = A[(size_t)(PHB_I0+cc)*256 + (PHB_I0+rr)];
  }
  __syncthreads();

  // ---------------- phase B: steps PHB_I0..254 in LDS ----------------------
  for (int i=PHB_I0;i<255;++i){
    int cb = (i - PHB_I0)*PHB_M;
    float alpha = Asub[cb + (i+1-PHB_I0)];
    float s=0.f;
    { int r=i+2+tid; if (r<256){ float a=Asub[cb + (r-PHB_I0)]; s=a*a; } }
    float xnorm2 = blk_reduce_sum512(s, red, tid);
    float tau=0.f, scale=0.f, beta=alpha;
    if (xnorm2 > 0.f){
      float r_ = sqrtf(alpha*alpha + xnorm2);
      beta = (alpha >= 0.f) ? -r_ : r_;
      tau = (beta - alpha)/beta;
      scale = 1.0f/(alpha - beta);
    }
    if (tid==0){ e_g[b*256+i] = beta; tau_g[b*256+i] = tau; }
    if (tau != 0.f){
      { int r=i+1+tid;
        if (r<256){
          float val = (r==i+1)?1.0f : Asub[cb+(r-PHB_I0)]*scale;
          Asub[cb+(r-PHB_I0)] = val;
          A[(size_t)i*256+r] = val;   // write-through: k_backtf reads this column
          v[r] = val;
        }
      }
      __syncthreads();
      int r = i+1+rid;
      bool rv = (r < 256);
      int ro = r - PHB_I0;
      int cmid = (i+1+256) >> 1;
      int cstart = (half==0)? (i+1) : cmid;
      int cend   = (half==0)? cmid  : 256;
      {
        float acc=0.f;
        if (rv){
          int nfull = (cend-cstart) >> 4;
          for (int t=0;t<nfull;++t){
            int cA = cstart + t*16;
            float av[16];
            #pragma unroll
            for (int u=0;u<16;++u) av[u] = Asub[(cA+u-PHB_I0)*PHB_M + ro];
            #pragma unroll
            for (int u=0;u<16;++u) acc = fmaf(av[u], v[cA+u], acc);
          }
          for (int c2=cstart+nfull*16;c2<cend;++c2)
            acc = fmaf(Asub[(c2-PHB_I0)*PHB_M+ro], v[c2], acc);
        }
        accbuf[half*256+rid] = acc;
      }
      __syncthreads();
      if (half==0 && rv) wv[r] = tau*(accbuf[rid] + accbuf[256+rid]);
      __syncthreads();
      float sd = (half==0 && rv)? v[r]*wv[r] : 0.f;
      float dotv = blk_reduce_sum512(sd, red, tid);
      float a2 = -0.5f*tau*dotv;
      if (half==0 && rv) wv[r] += a2*v[r];
      __syncthreads();
      if (rv){
        float vr=v[r], wr=wv[r];
        int nfull = (cend-cstart) >> 4;
        for (int t=0;t<nfull;++t){
          int cA=cstart+t*16;
          float av[16];
          #pragma unroll
          for (int u=0;u<16;++u) av[u] = Asub[(cA+u-PHB_I0)*PHB_M+ro];
          #pragma unroll
          for (int u=0;u<16;++u) av[u] -= vr*wv[cA+u] + wr*v[cA+u];
          #pragma unroll
          for (int u=0;u<16;++u) Asub[(cA+u-PHB_I0)*PHB_M+ro] = av[u];
        }
        for (int c2=cstart+nfull*16;c2<cend;++c2)
          Asub[(c2-PHB_I0)*PHB_M+ro] -= vr*wv[c2] + wr*v[c2];
      }
      __syncthreads();
    }
    __syncthreads();
  }
  if (tid < 256){
    int r = tid;
    float dv = (r >= PHB_I0)? Asub[(r-PHB_I0)*PHB_M + (r-PHB_I0)] : A[(size_t)r*256+r];
    d_g[b*256+r] = dv;
  }
}

// ------------------- leaves: lockstep wave-parallel Jacobi -------------------
__global__ __launch_bounds__(256) void k_leaf(const float* __restrict__ d_g,
                                              const float* __restrict__ e_g,
                                              float* __restrict__ Qg,
                                              double* __restrict__ Dw_g,
                                              double* __restrict__ emod_g){
  int b = blockIdx.x, tid = threadIdx.x;
  float* Q = Qg + (size_t)b*65536;
  double* Dw = Dw_g + (size_t)b*256;
  __shared__ double As[16*257];
  __shared__ float  Vt[16*257];
  __shared__ double dms[256];
  __shared__ double emod[256];
  __shared__ float redf[256];

  float dv = d_g[b*256+tid];
  float ev = (tid<255)? e_g[b*256+tid] : 0.f;
  redf[tid] = fmaxf(fabsf(dv), fabsf(ev)); __syncthreads();
  for(int o=128;o>0;o>>=1){ if(tid<o) redf[tid]=fmaxf(redf[tid],redf[tid+o]); __syncthreads(); }
  double sigma = (double)redf[0];
  if (!(sigma > 0.0)) sigma = 1.0;
  double dmod = (double)dv;
  if ((tid & 15)==15 && tid<255) dmod -= fabs((double)e_g[b*256+tid]);
  if ((tid & 15)==0  && tid>0)   dmod -= fabs((double)e_g[b*256+tid-1]);
  dmod /= sigma;
  double em = (tid<255)? ((double)ev)/sigma : 0.0;
  dms[tid] = dmod;  emod[tid] = em;
  emod_g[b*256+tid] = em;
  __syncthreads();

  int l16 = tid & ~15, j = tid & 15;
  for (int r=0;r<16;++r){
    double av = 0.0;
    if (r==j)        av = dms[l16+j];
    else if (r==j-1) av = emod[l16+j-1];
    else if (r==j+1) av = emod[l16+j];
    As[r*257+tid] = av;
    Vt[r*257+tid] = (r==j)? 1.f : 0.f;
  }
  __syncthreads();

  for (int sweep=0; sweep<14; ++sweep){
    for (int p=0;p<15;++p){
      for (int q=p+1;q<16;++q){
        double app = As[p*257 + l16+p];
        double aqq = As[q*257 + l16+q];
        double apq = As[p*257 + l16+q];
        bool rot = (fabs(apq) > 1e-18);
        double c, s;
        if (rot){
          double theta = (aqq - app)/(2.0*apq);
          double t = 1.0/(fabs(theta)+sqrt(1.0+theta*theta));
          if (theta < 0.0) t = -t;
          c = 1.0/sqrt(1.0+t*t); s = t*c;
        } else { c = 1.0; s = 0.0; }
        double apj = As[p*257 + tid];
        double aqj = As[q*257 + tid];
        double npj = c*apj - s*aqj;
        double nqj = s*apj + c*aqj;
        if (rot && j==p){ npj = c*c*app - 2.0*c*s*apq + s*s*aqq; nqj = 0.0; }
        if (rot && j==q){ npj = 0.0; nqj = s*s*app + 2.0*c*s*apq + c*c*aqq; }
        As[p*257 + tid] = npj;
        As[q*257 + tid] = nqj;
        As[j*257 + l16+p] = npj;
        As[j*257 + l16+q] = nqj;
        float vp = Vt[p*257 + tid], vq = Vt[q*257 + tid];
        Vt[p*257 + tid] = (float)(c*(double)vp - s*(double)vq);
        Vt[q*257 + tid] = (float)(s*(double)vp + c*(double)vq);
      }
    }
  }
  __syncthreads();
  double myval = As[j*257 + l16+j];
  int rank = 0;
  for (int k=0;k<16;++k){
    double vk = As[k*257 + l16+k];
    if (vk < myval || (vk==myval && k<j)) ++rank;
  }
  Dw[l16+rank] = myval;
  for (int r=0;r<16;++r)
    Q[(size_t)(l16+r)*256 + (l16+rank)] = Vt[j*257 + l16+r];
}

// ---------------- merge solve (slaed2 + secular), one block per merge --------
struct DCMerge {
  double z_[256], dsv[256], ds2[256], zs2[256];
  double dl_[256], zl_[256], taus[256], ztil[256], normk[256], evo[256];
  double rotcs[256][2];
  int    cs2[256], colx[256], non_[256], defl_[256], anch[256], osrc[256], otyp[256];
  int    roti[256][2];
};

// Global state layout, slot = b*8 + mrg, each array stride 256 per slot.
__global__ __launch_bounds__(256) void k_msolve(int lev,
                                                const double* __restrict__ emod_g,
                                                float* __restrict__ Qsrc,   // rotated in place
                                                double* __restrict__ Dw_g,
                                                double* __restrict__ Sdl,
                                                double* __restrict__ Sztil,
                                                double* __restrict__ Staus,
                                                double* __restrict__ Snk,
                                                int* __restrict__ Scolx,
                                                int* __restrict__ Sanch,
                                                int* __restrict__ Sotyp,
                                                int* __restrict__ Sosrc,
                                                int* __restrict__ SK){
  int mrg = blockIdx.x, b = blockIdx.y, tid = threadIdx.x;
  float* Q  = Qsrc + (size_t)b*65536;
  double* Dw = Dw_g + (size_t)b*256;
  int slot = b*8 + mrg;
  __shared__ DCMerge mg;
  __shared__ int bci[4];

  int ssz = 16<<lev, nm = ssz<<1;
  int base = mrg*nm;
  double rho0 = emod_g[b*256 + base+ssz-1];
  if (tid < nm){
    float zf = (tid < ssz) ? Q[(size_t)(base+ssz-1)*256 + base + tid]
                           : Q[(size_t)(base+ssz)*256   + base + tid];
    double zz = (double)zf;
    if (rho0 < 0.0 && tid >= ssz) zz = -zz;
    mg.z_[tid] = zz * 0.70710678118654752440;
    mg.dsv[tid] = Dw[base+tid];
  }
  __syncthreads();
  double rho = fabs(2.0*rho0);
  if (tid==0){
    int i1=0, i2=ssz, o=0;
    while (i1<ssz || i2<nm){
      bool take1;
      if (i1>=ssz) take1=false; else if (i2>=nm) take1=true;
      else take1 = (mg.dsv[i1] <= mg.dsv[i2]);
      int src = take1? i1++ : i2++;
      mg.ds2[o]=mg.dsv[src]; mg.zs2[o]=mg.z_[src]; mg.cs2[o]=src; ++o;
    }
  }
  __syncthreads();
  mg.taus[tid] = (tid<nm)? fabs(mg.zs2[tid]) : 0.0; __syncthreads();
  for(int o2=128;o2>0;o2>>=1){ if(tid<o2) mg.taus[tid]=fmax(mg.taus[tid],mg.taus[tid+o2]); __syncthreads(); }
  double zmax = mg.taus[0]; __syncthreads();
  mg.taus[tid] = (tid<nm)? fabs(mg.ds2[tid]) : 0.0; __syncthreads();
  for(int o2=128;o2>0;o2>>=1){ if(tid<o2) mg.taus[tid]=fmax(mg.taus[tid],mg.taus[tid+o2]); __syncthreads(); }
  double dmax = mg.taus[0]; __syncthreads();
  double tol = 8.0*LAPACK_EPS32*fmax(dmax, zmax);
  if (tid==0){
    int K=0, nd=0, nrot=0, pj=-1;
    for (int j=0;j<nm;++j){
      if (rho*fabs(mg.zs2[j]) <= tol){ mg.defl_[nd++]=j; continue; }
      if (pj>=0){
        double sg=mg.zs2[pj], cg=mg.zs2[j];
        double tg=mg.ds2[j]-mg.ds2[pj];
        double taug=sqrt(cg*cg+sg*sg);
        double cn, sn;
        if (taug > 0.0){ cn=cg/taug; sn=-sg/taug; } else { cn=1.0; sn=0.0; }
        if (fabs(tg*cn*sn) <= tol){
          mg.zs2[j]=taug; mg.zs2[pj]=0.0;
          mg.roti[nrot][0]=mg.cs2[pj]; mg.roti[nrot][1]=mg.cs2[j];
          mg.rotcs[nrot][0]=cn; mg.rotcs[nrot][1]=sn; ++nrot;
          double t2 = mg.ds2[pj]*cn*cn + mg.ds2[j]*sn*sn;
          mg.ds2[j] = mg.ds2[pj]*sn*sn + mg.ds2[j]*cn*cn;
          mg.ds2[pj] = t2;
          mg.defl_[nd++]=pj;
          pj=j;
        } else { mg.non_[K++]=pj; pj=j; }
      } else pj=j;
    }
    if (pj>=0) mg.non_[K++]=pj;
    bci[0]=K; bci[1]=nd; bci[2]=nrot;
  }
  __syncthreads();
  int K=bci[0], nd=bci[1], nrot=bci[2];
  // Givens rotations on src Q columns (in order)
  for (int r2=0;r2<nrot;++r2){
    int ca = base + mg.roti[r2][0], cb2 = base + mg.roti[r2][1];
    double cn = mg.rotcs[r2][0], sn = mg.rotcs[r2][1];
    if (tid < nm){
      int row = base+tid;
      float xv = Q[(size_t)row*256+ca], yv = Q[(size_t)row*256+cb2];
      Q[(size_t)row*256+ca]  = (float)(cn*(double)xv + sn*(double)yv);
      Q[(size_t)row*256+cb2] = (float)(cn*(double)yv - sn*(double)xv);
    }
    __syncthreads();
  }
  if (tid<K){
    mg.dl_[tid]=mg.ds2[mg.non_[tid]];
    mg.zl_[tid]=mg.zs2[mg.non_[tid]];
    mg.colx[tid]=mg.cs2[mg.non_[tid]];
  }
  __syncthreads();
  mg.taus[tid] = (tid<K)? mg.zl_[tid]*mg.zl_[tid] : 0.0; __syncthreads();
  for(int o2=128;o2>0;o2>>=1){ if(tid<o2) mg.taus[tid]+=mg.taus[tid+o2]; __syncthreads(); }
  double zsum2 = mg.taus[0]; __syncthreads();
  if (tid<K){
    int j=tid;
    double left=mg.dl_[j];
    double right=(j<K-1)? mg.dl_[j+1] : (mg.dl_[K-1] + rho*zsum2);
    double mid=0.5*(left+right);
    double fm=1.0;
    for (int i3=0;i3<K;++i3){
      double del=mg.dl_[i3]-mid;
      fm += rho*mg.zl_[i3]*mg.zl_[i3]/del;
    }
    int a; double lo, hi;
    if (j==K-1){
      a=K-1;
      if (fm<=0.0){ lo=mid-left; hi=right-left; } else { lo=0.0; hi=mid-left; }
    } else if (fm<=0.0){ a=j+1; lo=mid-mg.dl_[j+1]; hi=0.0; }
    else { a=j; lo=0.0; hi=mid-left; }
    double da2=mg.dl_[a];
    double t;
    if (hi > lo){
      t=0.5*(lo+hi);
    } else {
      t = (a==j)? 1e-300 : -1e-300;
      lo = fmin(lo, t); hi = fmax(hi, t);
    }
    for (int it=0; it<100; ++it){
      double gg=1.0, dg=0.0;
      for (int i3=0;i3<K;++i3){
        double del=(mg.dl_[i3]-da2)-t;
        double q=mg.zl_[i3]/del;
        gg += rho*mg.zl_[i3]*q;
        dg += rho*q*q;
      }
      if (gg<0.0) lo=t; else hi=t;
      double tn = t - gg/dg;
      if (!isfinite(tn) || !(tn>lo && tn<hi)) tn=0.5*(lo+hi);
      if (tn == 0.0) tn = (t!=0.0)? t*0.5 : ((a==j)?1e-300:-1e-300);
      double dstep=fabs(tn-t);
      t=tn;
      if (dstep <= 1e-15*(fabs(t)+1e-30)) break;
      if ((hi-lo) <= 1e-15*(fabs(da2)+fabs(t)+1e-30)) break;
    }
    if (t == 0.0 || !isfinite(t)) t = (a==j)? 1e-300 : -1e-300;
    mg.taus[j]=t; mg.anch[j]=a;
  }
  __syncthreads();
  if (tid<K){
    int i3=tid; double acc=0.0; double di=mg.dl_[i3];
    for (int j=0;j<K;++j){
      double lmd = (mg.dl_[mg.anch[j]] - di) + mg.taus[j];
      acc += safelog(lmd);
      if (j!=i3) acc -= safelog(mg.dl_[j]-di);
    }
    double mag = exp(0.5*acc);
    if (!isfinite(mag)) mag = 0.0;
    mg.ztil[i3] = (mg.zl_[i3] >= 0.0)? mag : -mag;
  }
  __syncthreads();
  if (tid<K){
    int j=tid; double da2=mg.dl_[mg.anch[j]]; double tj=mg.taus[j];
    double nr=0.0;
    for (int i3=0;i3<K;++i3){
      double del=(mg.dl_[i3]-da2)-tj;
      if (del == 0.0) del = (tj>=0.0)? -1e-300 : 1e-300;
      double sv=mg.ztil[i3]/del;
      nr += sv*sv;
    }
    if (!(nr > 0.0) || !isfinite(nr)) nr = 1.0;
    mg.normk[j]=sqrt(nr);
  }
  __syncthreads();
  // output ordering
  if (tid==0){
    for (int a2=1;a2<nd;++a2){
      int key=mg.defl_[a2]; double kv=mg.ds2[key]; int b2=a2-1;
      while (b2>=0 && mg.ds2[mg.defl_[b2]] > kv){ mg.defl_[b2+1]=mg.defl_[b2]; --b2; }
      mg.defl_[b2+1]=key;
    }
    int i1=0,i2=0,o=0;
    while (i1<K || i2<nd){
      double v1 = (i1<K)? (mg.dl_[mg.anch[i1]]+mg.taus[i1]) : 0.0;
      double v2 = (i2<nd)? mg.ds2[mg.defl_[i2]] : 0.0;
      bool take1;
      if (i1>=K) take1=false; else if (i2>=nd) take1=true; else take1 = (v1 <= v2);
      if (take1){ mg.otyp[o]=0; mg.osrc[o]=i1; mg.evo[o]=v1; ++i1; }
      else { mg.otyp[o]=1; mg.osrc[o]=mg.cs2[mg.defl_[i2]]; mg.evo[o]=v2; ++i2; }
      ++o;
    }
  }
  __syncthreads();
  if (tid<nm) Dw[base+tid]=mg.evo[tid];
  // write state
  size_t so = (size_t)slot*256;
  if (tid<K){
    Sdl[so+tid]=mg.dl_[tid]; Sztil[so+tid]=mg.ztil[tid];
    Staus[so+tid]=mg.taus[tid]; Snk[so+tid]=mg.normk[tid];
    Scolx[so+tid]=mg.colx[tid]; Sanch[so+tid]=mg.anch[tid];
  }
  if (tid<nm){ Sotyp[so+tid]=mg.otyp[tid]; Sosrc[so+tid]=mg.osrc[tid]; }
  if (tid==0) SK[slot]=K;
}

// ---------------- merge assemble: Qdst[:,p] = Qsrc_sub @ svf  ----------------
// grid: (nm/16 col-tiles, nmerge, 16 batches); block 256.
__global__ __launch_bounds__(256) void k_mvec(int lev,
                                              const float* __restrict__ Qsrc_g,
                                              float* __restrict__ Qdst_g,
                                              const double* __restrict__ Sdl,
                                              const double* __restrict__ Sztil,
                                              const double* __restrict__ Staus,
                                              const double* __restrict__ Snk,
                                              const int* __restrict__ Scolx,
                                              const int* __restrict__ Sanch,
                                              const int* __restrict__ Sotyp,
                                              const int* __restrict__ Sosrc,
                                              const int* __restrict__ SK){
  int t = blockIdx.x, mrg = blockIdx.y, b = blockIdx.z, tid = threadIdx.x;
  const float* Q = Qsrc_g + (size_t)b*65536;
  float* Qd = Qdst_g + (size_t)b*65536;
  int slot = b*8 + mrg;
  size_t so = (size_t)slot*256;
  int ssz = 16<<lev, nm = ssz<<1;
  int base = mrg*nm;
  int p0 = t*16;
  int K = SK[slot];

  __shared__ float svf[256*16];      // [i3][c], stride 16: compute idx==tid -> conflict-free
  __shared__ double cda[16], ctj[16];
  __shared__ float cnk[16];
  __shared__ int ctyp[16], csrc[16];

  if (tid < 16){
    int p = p0 + tid;
    int typ = Sotyp[so+p], src = Sosrc[so+p];
    ctyp[tid]=typ; csrc[tid]=src;
    if (typ==0){
      int j = src;
      cda[tid] = Sdl[so + Sanch[so+j] - 0 + 0];    // placeholder; fixed below
    }
  }
  __syncthreads();
  // fix cda/ctj/cnk properly (need anch lookup)
  if (tid < 16){
    int p = p0 + tid;
    if (ctyp[tid]==0){
      int j = csrc[tid];
      int a = Sanch[so+j];
      cda[tid] = Sdl[so+a];
      ctj[tid] = Staus[so+j];
      cnk[tid] = (float)Snk[so+j];
    } else { cda[tid]=0.0; ctj[tid]=1.0; cnk[tid]=1.f; }
  }
  __syncthreads();
  // build svf tile
  for (int idx = tid; idx < K*16; idx += 256){
    int i3 = idx >> 4, c = idx & 15;
    float sv = 0.f;
    if (ctyp[c]==0){
      double del = (Sdl[so+i3] - cda[c]) - ctj[c];
      if (del == 0.0) del = (ctj[c]>=0.0)? -1e-300 : 1e-300;
      sv = (float)( Sztil[so+i3]/del / (double)cnk[c] );
      if (!isfinite(sv)) sv = 0.f;
    }
    svf[i3*16 + c] = sv;
  }
  __syncthreads();

  // rows: one thread per row (nm <= 256)
  if (tid < nm){
    int row = base + tid;
    const float* Qr = Q + (size_t)row*256 + base;
    float acc[16];
    #pragma unroll
    for (int c=0;c<16;++c) acc[c]=0.f;
    for (int i3=0;i3<K;++i3){
      float qv = Qr[Scolx[so+i3]];
      #pragma unroll
      for (int c=0;c<16;++c) acc[c] = fmaf(qv, svf[i3*16+c], acc[c]);
    }
    #pragma unroll
    for (int c=0;c<16;++c){
      float v = acc[c];
      if (ctyp[c]==1) v = Qr[csrc[c]];
      if (!isfinite(v)) v = 0.f;
      Qd[(size_t)row*256 + base + p0 + c] = v;
    }
  }
}

// --------------- back-transform: U16 = H_1...H_255 * Vtri[:,240:256] ---------
// 512 threads (measured win in R14/R15): 32 row-groups x 8 rows.
__global__ __launch_bounds__(512,1) void k_backtf(const float* __restrict__ Ag,
                                                  const float* __restrict__ tau_g,
                                                  const float* __restrict__ Qg,
                                                  float* __restrict__ w16g){
  int b=blockIdx.x, tid=threadIdx.x;
  const float* A=Ag+(size_t)b*65536;
  const float* Q=Qg+(size_t)b*65536;
  __shared__ float U[256][17];
  __shared__ float pd[32][17];
  __shared__ float dk[16];
  int k=tid&15, rg=tid>>4;   // rg in 0..31
  for (int r=rg;r<256;r+=32) U[r][k]=Q[(size_t)r*256+240+k];
  __syncthreads();
  for (int i=254;i>=0;--i){
    float tau=tau_g[b*256+i];
    if (tau!=0.f){
      int r0 = i+1+rg;
      float ar[8];
      #pragma unroll
      for (int u=0;u<8;++u){
        int r = r0 + u*32;
        ar[u] = (r<256)? A[(size_t)i*256+r] : 0.f;
      }
      float uv[8];
      #pragma unroll
      for (int u=0;u<8;++u){
        int r = r0 + u*32;
        uv[u] = (r<256)? U[r][k] : 0.f;
      }
      float s=0.f;
      #pragma unroll
      for (int u=0;u<8;++u){
        int r = r0 + u*32;
        if (r<256) s += ar[u]*uv[u];
      }
      pd[rg][k]=s;
      __syncthreads();
      if (tid<16){
        float acc=0.f;
        #pragma unroll
        for (int gg=0; gg<32; ++gg) acc+=pd[gg][tid];
        dk[tid]=tau*acc;
      }
      __syncthreads();
      float dkk = dk[k];
      #pragma unroll
      for (int u=0;u<8;++u){
        int r = r0 + u*32;
        if (r<256) U[r][k] -= dkk*ar[u];
      }
      __syncthreads();
    }
  }
  for (int c2=rg;c2<256;c2+=32){
    float uv = U[c2][k];
    if (!isfinite(uv)) uv = 0.f;
    w16g[((size_t)b*16+k)*256+c2]=uv;
  }
}

// ---------------- fused scores + softmax + y (replaces k_score/k_y) ----------
// Each thread owns column n of g: reads all 256 channels (score, identical
// FP sequence to old k_score), softmaxes, then writes y over the same column
// (identical FP sequence to old k_y). z never materialized. No cross-thread
// sharing of g columns -> race-free in-place. Bit-exact (R16 measured).
__global__ __launch_bounds__(256) void k_scy(float* __restrict__ g,
                                             const float* __restrict__ w16){
  __shared__ __attribute__((aligned(16))) float ws[256][16];   // [c2][k2]
  int nt=blockIdx.x, b=blockIdx.y, tid=threadIdx.x;
  for (int i=tid;i<4096;i+=256) ws[i&255][i>>8]=w16[(size_t)b*4096+i];
  __syncthreads();
  int n=nt*256+tid;
  float* gp=g+(size_t)b*NC*NSP+n;
  float acc[16];
  #pragma unroll
  for(int k2=0;k2<16;++k2) acc[k2]=0.f;
  for (int c2=0;c2<256;++c2){
    float gv=gp[(size_t)c2*NSP];
    float4 wa=*(const float4*)&ws[c2][0];
    float4 wb=*(const float4*)&ws[c2][4];
    float4 wc=*(const float4*)&ws[c2][8];
    float4 wd=*(const float4*)&ws[c2][12];
    acc[0] =fmaf(wa.x,gv,acc[0]);  acc[1] =fmaf(wa.y,gv,acc[1]);
    acc[2] =fmaf(wa.z,gv,acc[2]);  acc[3] =fmaf(wa.w,gv,acc[3]);
    acc[4] =fmaf(wb.x,gv,acc[4]);  acc[5] =fmaf(wb.y,gv,acc[5]);
    acc[6] =fmaf(wb.z,gv,acc[6]);  acc[7] =fmaf(wb.w,gv,acc[7]);
    acc[8] =fmaf(wc.x,gv,acc[8]);  acc[9] =fmaf(wc.y,gv,acc[9]);
    acc[10]=fmaf(wc.z,gv,acc[10]); acc[11]=fmaf(wc.w,gv,acc[11]);
    acc[12]=fmaf(wd.x,gv,acc[12]); acc[13]=fmaf(wd.y,gv,acc[13]);
    acc[14]=fmaf(wd.z,gv,acc[14]); acc[15]=fmaf(wd.w,gv,acc[15]);
  }
  float mx=-1e30f;
  #pragma unroll
  for(int k2=0;k2<16;++k2){ acc[k2]*=3.0f; mx=fmaxf(mx,acc[k2]); }
  float sum=0.f;
  #pragma unroll
  for(int k2=0;k2<16;++k2){ acc[k2]=expf(acc[k2]-mx); sum+=acc[k2]; }
  float inv=1.0f/sum;
  #pragma unroll
  for(int k2=0;k2<16;++k2) acc[k2]*=inv;     // z values, identical to old path
  for (int c2=0;c2<256;++c2){
    float4 wa=*(const float4*)&ws[c2][0];
    float4 wb=*(const float4*)&ws[c2][4];
    float4 wc=*(const float4*)&ws[c2][8];
    float4 wd=*(const float4*)&ws[c2][12];
    float a=0.f;
    a=fmaf(wa.x,acc[0],a);  a=fmaf(wa.y,acc[1],a);
    a=fmaf(wa.z,acc[2],a);  a=fmaf(wa.w,acc[3],a);
    a=fmaf(wb.x,acc[4],a);  a=fmaf(wb.y,acc[5],a);
    a=fmaf(wb.z,acc[6],a);  a=fmaf(wb.w,acc[7],a);
    a=fmaf(wc.x,acc[8],a);  a=fmaf(wc.y,acc[9],a);
    a=fmaf(wc.z,acc[10],a); a=fmaf(wc.w,acc[11],a);
    a=fmaf(wd.x,acc[12],a); a=fmaf(wd.y,acc[13],a);
    a=fmaf(wd.z,acc[14],a); a=fmaf(wd.w,acc[15],a);
    gp[(size_t)c2*NSP]=a;
  }
}

// ------------------------- conv2(3x3) + BN + residual ------------------------
// Round-5 form VERBATIM (1832us known-good): cc-outer, dd fully unrolled,
// unpadded wt[16][8][9], scalar broadcast reads, 1 output/thread, ht=16.
// CLOSED: three restructure attempts (R11/R12/R16) all regressed.
__global__ __launch_bounds__(256) void k_conv2(const float* __restrict__ y,
                                               const void* __restrict__ w2v,
                                               const void* __restrict__ xv_,
                                               const void* __restrict__ gmv,
                                               const void* __restrict__ btv,
                                               const void* __restrict__ muv,
                                               const void* __restrict__ vrv,
                                               const int* __restrict__ flags,
                                               void* __restrict__ outv){
  __shared__ float yt[8][6][66];
  __shared__ float wt[16][8][9];
  int ht=blockIdx.x, ct=blockIdx.y, b=blockIdx.z, tid=threadIdx.x;
  int hl=tid>>6, wl=tid&63;
  int h=ht*4+hl;
  int c0=ct*16;
  int isf = flags[0];
  float acc[16];
  #pragma unroll
  for(int i=0;i<16;++i) acc[i]=0.f;
  const float* yb = y + (size_t)b*NC*NSP;
  for (int d0=0; d0<256; d0+=8){
    for (int idx=tid; idx<8*6*64; idx+=256){
      int dd=idx/384; int rem=idx-dd*384; int rr=rem>>6; int cc2=rem&63;
      int hg=ht*4-1+rr;
      float v = (hg>=0 && hg<64)? yb[(size_t)(d0+dd)*NSP + hg*64 + cc2] : 0.f;
      yt[dd][rr][cc2+1]=v;
    }
    if (tid<48){ int dd=tid/6, rr=tid-dd*6; yt[dd][rr][0]=0.f; yt[dd][rr][65]=0.f; }
    if (isf){
      const float* w2 = (const float*)w2v;
      for (int idx=tid; idx<16*8*9; idx+=256){
        int cc=idx/72; int rem=idx-cc*72; int dd=rem/9; int kk=rem-dd*9;
        wt[cc][dd][kk]=w2[ ((size_t)(c0+cc)*256 + d0+dd)*9 + kk ];
      }
    } else {
      const bf16* w2 = (const bf16*)w2v;
      for (int idx=tid; idx<16*8*9; idx+=256){
        int cc=idx/72; int rem=idx-cc*72; int dd=rem/9; int kk=rem-dd*9;
        wt[cc][dd][kk]=b2f(w2[ ((size_t)(c0+cc)*256 + d0+dd)*9 + kk ]);
      }
    }
    __syncthreads();
    for (int cc=0; cc<16; ++cc){
      float a=acc[cc];
      #pragma unroll
      for (int dd=0; dd<8; ++dd){
        const float* wp=wt[cc][dd];
        a = fmaf(wp[0], yt[dd][hl+0][wl+0], a);
        a = fmaf(wp[1], yt[dd][hl+0][wl+1], a);
        a = fmaf(wp[2], yt[dd][hl+0][wl+2], a);
        a = fmaf(wp[3], yt[dd][hl+1][wl+0], a);
        a = fmaf(wp[4], yt[dd][hl+1][wl+1], a);
        a = fmaf(wp[5], yt[dd][hl+1][wl+2], a);
        a = fmaf(wp[6], yt[dd][hl+2][wl+0], a);
        a = fmaf(wp[7], yt[dd][hl+2][wl+1], a);
        a = fmaf(wp[8], yt[dd][hl+2][wl+2], a);
      }
      acc[cc]=a;
    }
    __syncthreads();
  }
  size_t nidx=(size_t)h*64+wl;
  for (int cc=0;cc<16;++cc){
    int c=c0+cc;
    float gmf, btf, muf, vrf, xvv;
    size_t oi = ((size_t)b*NC+c)*NSP + nidx;
    if (isf){
      gmf=((const float*)gmv)[c]; btf=((const float*)btv)[c];
      muf=((const float*)muv)[c]; vrf=((const float*)vrv)[c];
      xvv=((const float*)xv_)[oi];
    } else {
      gmf=b2f(((const bf16*)gmv)[c]); btf=b2f(((const bf16*)btv)[c]);
      muf=b2f(((const bf16*)muv)[c]); vrf=b2f(((const bf16*)vrv)[c]);
      xvv=b2f(((const bf16*)xv_)[oi]);
    }
    float inv = gmf * rsqrtf(vrf + 1e-5f);
    float shift = btf - muf*inv;
    float val = xvv + acc[cc]*inv + shift;
    if (isf) ((float*)outv)[oi] = val;
    else     ((bf16*)outv)[oi] = __float2bfloat16(val);
  }
}

// ---------------------------------------------------------------------------
extern "C" void kernel_launch(void* const* d_in, const int* in_sizes, int n_in,
                              void* d_out, int out_size, void* d_ws, size_t ws_size,
                              hipStream_t stream) {
  const void* x   = d_in[0];
  const void* w1  = d_in[1];
  // d_in[2] = conv1_b: constant over spatial -> cancelled by centering; unused.
  const void* w2  = d_in[3];
  const void* gmm = d_in[4];
  const void* bet = d_in[5];
  const void* mu  = d_in[6];
  const void* var = d_in[7];

  float* g    = (float*)d_ws;                      // 16*256*4096 (later reused as y)
  float* A    = g   + (size_t)NB*NC*NSP;
  float* Qa   = A   + (size_t)NB*NC*NC;
  float* Qb   = Qa  + (size_t)NB*NC*NC;
  float* w16  = Qb  + (size_t)NB*NC*NC;
  float* zb   = w16 + (size_t)NB*16*NC;            // unused since R16 fusion
  float* e_g  = zb  + (size_t)NB*16*NSP;
  float* tau_g= e_g + (size_t)NB*NC;
  float* d_g  = tau_g + (size_t)NB*NC;
  double* Dw  = (double*)(d_g + (size_t)NB*NC);
  double* emod_g = Dw + (size_t)NB*NC;
  double* Sdl   = emod_g + (size_t)NB*NC;
  double* Sztil = Sdl   + (size_t)128*256;
  double* Staus = Sztil + (size_t)128*256;
  double* Snk   = Staus + (size_t)128*256;
  int* Scolx = (int*)(Snk + (size_t)128*256);
  int* Sanch = Scolx + (size_t)128*256;
  int* Sotyp = Sanch + (size_t)128*256;
  int* Sosrc = Sotyp + (size_t)128*256;
  int* SK    = Sosrc + (size_t)128*256;
  int* flags = SK + 256;
  size_t needed = (size_t)((char*)(flags + 16) - (char*)d_ws);
  if (ws_size < needed) return;

  hipMemsetAsync(Qa, 0, (size_t)NB*NC*NC*2*sizeof(float), stream);  // Qa+Qb contiguous
  k_detect<<<dim3(1),256,0,stream>>>((const unsigned short*)x, flags);
  k_conv1 <<<dim3(16,16,16),256,0,stream>>>(x, w1, flags, g);
  k_center<<<dim3(NB*NC),256,0,stream>>>(g);
  k_cmat  <<<dim3(8,8,16),256,0,stream>>>(g, A);
  k_sytd2 <<<dim3(16),512,0,stream>>>(A, e_g, tau_g, d_g);
  k_leaf  <<<dim3(16),256,0,stream>>>(d_g, e_g, Qa, Dw, emod_g);
  // lev0: Qa -> Qb
  k_msolve<<<dim3(8,16),256,0,stream>>>(0, emod_g, Qa, Dw, Sdl,Sztil,Staus,Snk,Scolx,Sanch,Sotyp,Sosrc,SK);
  k_mvec  <<<dim3(2,8,16),256,0,stream>>>(0, Qa, Qb, Sdl,Sztil,Staus,Snk,Scolx,Sanch,Sotyp,Sosrc,SK);
  // lev1: Qb -> Qa
  k_msolve<<<dim3(4,16),256,0,stream>>>(1, emod_g, Qb, Dw, Sdl,Sztil,Staus,Snk,Scolx,Sanch,Sotyp,Sosrc,SK);
  k_mvec  <<<dim3(4,4,16),256,0,stream>>>(1, Qb, Qa, Sdl,Sztil,Staus,Snk,Scolx,Sanch,Sotyp,Sosrc,SK);
  // lev2: Qa -> Qb
  k_msolve<<<dim3(2,16),256,0,stream>>>(2, emod_g, Qa, Dw, Sdl,Sztil,Staus,Snk,Scolx,Sanch,Sotyp,Sosrc,SK);
  k_mvec  <<<dim3(8,2,16),256,0,stream>>>(2, Qa, Qb, Sdl,Sztil,Staus,Snk,Scolx,Sanch,Sotyp,Sosrc,SK);
  // lev3: Qb -> Qa
  k_msolve<<<dim3(1,16),256,0,stream>>>(3, emod_g, Qb, Dw, Sdl,Sztil,Staus,Snk,Scolx,Sanch,Sotyp,Sosrc,SK);
  k_mvec  <<<dim3(16,1,16),256,0,stream>>>(3, Qb, Qa, Sdl,Sztil,Staus,Snk,Scolx,Sanch,Sotyp,Sosrc,SK);
  k_backtf<<<dim3(16),512,0,stream>>>(A, tau_g, Qa, w16);
  k_scy   <<<dim3(16,16),256,0,stream>>>(g, w16);       // fused score+softmax+y (in-place)
  k_conv2 <<<dim3(16,16,16),256,0,stream>>>(g, w2, x, gmm, bet, mu, var, flags, d_out);
}

// Round 13
// 7426.386 us; speedup vs baseline: 1.2673x; 1.0021x over previous
//
#include <hip/hip_runtime.h>
#include <hip/hip_bf16.h>
#include <math.h>

// ---------------------------------------------------------------------------
// SAPCABlockV5: conv1(1x1) -> center -> per-batch covariance -> eigh(top16)
//               -> softmax projection -> conv2(3x3) + BN + residual
// B=16, C=256, H=W=64, N=4096. Internal compute f32/f64. Dual dtype paths
// (bf16/f32) runtime-detected from x's bit patterns.
//
// eigh: faithful-skeleton ssyevd.
// Round-18 (this): k_cmat 2-cols-per-thread. 32x64 tile, grid (4,8,16)=512
//   blocks; thread computes 4 rows x 2 cols (tx, tx+32). Per kk: 4 t1 + 2 t2
//   LDS reads feed 8 FMAs (0.75 reads/FMA vs 1.25) -> ~27% fewer issue
//   slots. Acc 4->8 VGPRs only (NOT the conv2 failure mode: no unrolled-body
//   x2 blowup). t2[tx][kk] = 2 lanes/bank (free); t1 reads broadcast.
//   Per-output FMA order (ch asc, kk asc, operand order) unchanged ->
//   bit-identical. Global traffic 1.07GB -> 0.81GB.
//   FROZEN: conv2 = R5 verbatim (CLOSED after 3 failed restructures),
//   sytd2 512-thread (1024 regressed), backtf 512, conv1/scy float4,
//   center/leaf/msolve/mvec. absmax must stay EXACTLY 0.015625.
// ---------------------------------------------------------------------------

typedef __hip_bfloat16 bf16;

#define NB 16
#define NC 256
#define NSP 4096
#define LAPACK_EPS32 5.9604644775390625e-08

#define PHB_I0 80
#define PHB_M  176   // 256 - PHB_I0; 176*176*4B = 123904B LDS

__device__ __forceinline__ float b2f(bf16 v){ return __bfloat162float(v); }
__device__ __forceinline__ double safelog(double x){
  double a = fabs(x);
  if (!(a > 0.0) || !isfinite(a)) a = 1e-300;
  return log(a);
}

// 256-thread block-wide sum (used by unchanged kernels).
__device__ __forceinline__ float blk_reduce_sum(float s, float* red, int tid){
  red[tid] = s; __syncthreads();
  if (tid < 128) red[tid] += red[tid+128];
  __syncthreads();
  if (tid < 64){
    float x = red[tid] + red[tid+64];
    #pragma unroll
    for (int o = 32; o > 0; o >>= 1) x += __shfl_down(x, o);
    if (tid == 0) red[0] = x;
  }
  __syncthreads();
  return red[0];
}

// 512-thread block-wide sum.
__device__ __forceinline__ float blk_reduce_sum512(float s, float* red, int tid){
  red[tid] = s; __syncthreads();
  if (tid < 256) red[tid] += red[tid+256];
  __syncthreads();
  if (tid < 128) red[tid] += red[tid+128];
  __syncthreads();
  if (tid < 64){
    float x = red[tid] + red[tid+64];
    #pragma unroll
    for (int o = 32; o > 0; o >>= 1) x += __shfl_down(x, o);
    if (tid == 0) red[0] = x;
  }
  __syncthreads();
  return red[0];
}

// ------------------------- dtype probe --------------------------------------
__global__ __launch_bounds__(256) void k_detect(const unsigned short* __restrict__ xr,
                                                int* __restrict__ flags){
  __shared__ int red[256];
  int tid = threadIdx.x;
  int cnt = 0;
  for (int i = tid; i < 4096; i += 256){
    unsigned int u = xr[i];
    unsigned int e = (u >> 7) & 0xFF;
    if (e >= 134) ++cnt;
  }
  red[tid] = cnt; __syncthreads();
  for (int o=128;o>0;o>>=1){ if(tid<o) red[tid]+=red[tid+o]; __syncthreads(); }
  if (tid==0) flags[0] = (red[0] > 50) ? 1 : 0;   // 1 = inputs are f32
}

// ------------------------- conv1 (1x1) : g = W1 @ x --------------------------
// ws transposed to [d][ci] + float4 uniform reads (bit-exact since R13).
__global__ __launch_bounds__(256) void k_conv1(const void* __restrict__ xv_,
                                               const void* __restrict__ w1v,
                                               const int* __restrict__ flags,
                                               float* __restrict__ g){
  __shared__ __attribute__((aligned(16))) float ws[256][16];   // [d][ci]
  int nt = blockIdx.x, ct = blockIdx.y, b = blockIdx.z;
  int tid = threadIdx.x;
  int c0 = ct*16;
  int isf = flags[0];
  if (isf){
    const float* w1 = (const float*)w1v;
    for (int i = tid; i < 16*256; i += 256)
      ws[i&255][i>>8] = w1[(size_t)(c0 + (i>>8))*256 + (i&255)];
  } else {
    const bf16* w1 = (const bf16*)w1v;
    for (int i = tid; i < 16*256; i += 256)
      ws[i&255][i>>8] = b2f(w1[(size_t)(c0 + (i>>8))*256 + (i&255)]);
  }
  __syncthreads();
  int n = nt*256 + tid;
  float acc[16];
  #pragma unroll
  for (int i=0;i<16;++i) acc[i]=0.f;
  if (isf){
    const float* xp = (const float*)xv_ + (size_t)b*NC*NSP + n;
    for (int d=0; d<256; ++d){
      float xv = xp[(size_t)d*NSP];
      float4 wa=*(const float4*)&ws[d][0];
      float4 wb=*(const float4*)&ws[d][4];
      float4 wc=*(const float4*)&ws[d][8];
      float4 wd=*(const float4*)&ws[d][12];
      acc[0] =fmaf(wa.x,xv,acc[0]);  acc[1] =fmaf(wa.y,xv,acc[1]);
      acc[2] =fmaf(wa.z,xv,acc[2]);  acc[3] =fmaf(wa.w,xv,acc[3]);
      acc[4] =fmaf(wb.x,xv,acc[4]);  acc[5] =fmaf(wb.y,xv,acc[5]);
      acc[6] =fmaf(wb.z,xv,acc[6]);  acc[7] =fmaf(wb.w,xv,acc[7]);
      acc[8] =fmaf(wc.x,xv,acc[8]);  acc[9] =fmaf(wc.y,xv,acc[9]);
      acc[10]=fmaf(wc.z,xv,acc[10]); acc[11]=fmaf(wc.w,xv,acc[11]);
      acc[12]=fmaf(wd.x,xv,acc[12]); acc[13]=fmaf(wd.y,xv,acc[13]);
      acc[14]=fmaf(wd.z,xv,acc[14]); acc[15]=fmaf(wd.w,xv,acc[15]);
    }
  } else {
    const bf16* xp = (const bf16*)xv_ + (size_t)b*NC*NSP + n;
    for (int d=0; d<256; ++d){
      float xv = b2f(xp[(size_t)d*NSP]);
      float4 wa=*(const float4*)&ws[d][0];
      float4 wb=*(const float4*)&ws[d][4];
      float4 wc=*(const float4*)&ws[d][8];
      float4 wd=*(const float4*)&ws[d][12];
      acc[0] =fmaf(wa.x,xv,acc[0]);  acc[1] =fmaf(wa.y,xv,acc[1]);
      acc[2] =fmaf(wa.z,xv,acc[2]);  acc[3] =fmaf(wa.w,xv,acc[3]);
      acc[4] =fmaf(wb.x,xv,acc[4]);  acc[5] =fmaf(wb.y,xv,acc[5]);
      acc[6] =fmaf(wb.z,xv,acc[6]);  acc[7] =fmaf(wb.w,xv,acc[7]);
      acc[8] =fmaf(wc.x,xv,acc[8]);  acc[9] =fmaf(wc.y,xv,acc[9]);
      acc[10]=fmaf(wc.z,xv,acc[10]); acc[11]=fmaf(wc.w,xv,acc[11]);
      acc[12]=fmaf(wd.x,xv,acc[12]); acc[13]=fmaf(wd.y,xv,acc[13]);
      acc[14]=fmaf(wd.z,xv,acc[14]); acc[15]=fmaf(wd.w,xv,acc[15]);
    }
  }
  float* gp = g + ((size_t)b*NC + c0)*NSP + n;
  #pragma unroll
  for (int i=0;i<16;++i) gp[(size_t)i*NSP] = acc[i];
}

// ------------------------- center over spatial -------------------------------
__global__ __launch_bounds__(256) void k_center(float* __restrict__ g){
  int bc = blockIdx.x;
  float* p = g + (size_t)bc*NSP;
  int tid = threadIdx.x;
  __shared__ float red[256];
  float s = 0.f;
  for (int i=tid;i<NSP;i+=256) s += p[i];
  red[tid]=s; __syncthreads();
  for (int o=128;o>0;o>>=1){ if(tid<o) red[tid]+=red[tid+o]; __syncthreads(); }
  float mean = red[0] * (1.0f/4096.0f);
  for (int i=tid;i<NSP;i+=256) p[i] -= mean;
}

// ------------------------- cmat = g g^T / 16 ---------------------------------
// Round-18: 32x64 tile, 4 rows x 2 cols per thread. Per kk: 4 t1 + 2 t2 LDS
// reads -> 8 FMAs (0.75 reads/FMA vs 1.25). Per-output k-order (ch asc, kk
// asc) and operand order unchanged -> bit-identical. Grid (4,8,16).
__global__ __launch_bounds__(256) void k_cmat(const float* __restrict__ g,
                                              float* __restrict__ A){
  __shared__ float t1[32][65];
  __shared__ float t2[64][65];
  int bx = blockIdx.x, by = blockIdx.y, b = blockIdx.z;
  int tid = threadIdx.x;
  int tx = tid & 31, ty = tid >> 5;
  const float* gb = g + (size_t)b*NC*NSP;
  float accA[4] = {0.f,0.f,0.f,0.f};
  float accB[4] = {0.f,0.f,0.f,0.f};
  for (int ch=0; ch<64; ++ch){
    int n0 = ch*64;
    for (int idx=tid; idx<2048; idx+=256){
      int r = idx>>6, cc = idx&63;
      t1[r][cc] = gb[(size_t)(by*32 + r)*NSP + n0 + cc];
    }
    for (int idx=tid; idx<4096; idx+=256){
      int r = idx>>6, cc = idx&63;
      t2[r][cc] = gb[(size_t)(bx*64 + r)*NSP + n0 + cc];
    }
    __syncthreads();
    for (int kk=0; kk<64; ++kk){
      float v2a = t2[tx][kk];
      float v2b = t2[tx+32][kk];
      #pragma unroll
      for (int jj=0;jj<4;++jj){
        float t1v = t1[ty+8*jj][kk];
        accA[jj] = fmaf(t1v, v2a, accA[jj]);
        accB[jj] = fmaf(t1v, v2b, accB[jj]);
      }
    }
    __syncthreads();
  }
  #pragma unroll
  for (int jj=0;jj<4;++jj){
    int row = by*32 + ty + 8*jj;
    int colA = bx*64 + tx;
    A[((size_t)b*NC + row)*NC + colA]      = accA[jj]*(1.0f/16.0f);
    A[((size_t)b*NC + row)*NC + colA + 32] = accB[jj]*(1.0f/16.0f);
  }
}

// ------------------------- sytd2 (LAPACK 'L'), transposed addressing ---------
// 512 threads (PROVEN best): rid=tid&255 -> row i+1+rid, half=tid>>8 ->
// column half. 1024-thread quarter split regressed (R14); do not raise.
__global__ __launch_bounds__(512,1) void k_sytd2(float* __restrict__ Ag,
                                                 float* __restrict__ e_g,
                                                 float* __restrict__ tau_g,
                                                 float* __restrict__ d_g){
  int b = blockIdx.x, tid = threadIdx.x;
  int rid = tid & 255, half = tid >> 8;
  float* A = Ag + (size_t)b*65536;
  __shared__ float Asub[PHB_M*PHB_M];
  __shared__ float v[256], wv[256];
  __shared__ float red[512];
  __shared__ float accbuf[512];

  // ---------------- phase A: steps 0..PHB_I0-1 on global A -----------------
  for (int i=0;i<PHB_I0;++i){
    float alpha = A[(size_t)i*256+(i+1)];
    float s=0.f;
    { int r=i+2+tid; if (r<256){ float a=A[(size_t)i*256+r]; s=a*a; } }
    float xnorm2 = blk_reduce_sum512(s, red, tid);
    float tau=0.f, scale=0.f, beta=alpha;
    if (xnorm2 > 0.f){
      float r_ = sqrtf(alpha*alpha + xnorm2);
      beta = (alpha >= 0.f) ? -r_ : r_;       // -SIGN(r, alpha)
      tau = (beta - alpha)/beta;
      scale = 1.0f/(alpha - beta);
    }
    if (tid==0){ e_g[b*256+i] = beta; tau_g[b*256+i] = tau; }
    if (tau != 0.f){
      { int r=i+1+tid;
        if (r<256){
          float val = (r==i+1)?1.0f : A[(size_t)i*256+r]*scale;
          A[(size_t)i*256+r] = val;  v[r] = val;
        }
      }
      __syncthreads();
      int r = i+1+rid;
      bool rv = (r < 256);
      int cmid = (i+1+256) >> 1;
      int cstart = (half==0)? (i+1) : cmid;
      int cend   = (half==0)? cmid  : 256;
      // ---- matvec half: acc = sum_{c in [cstart,cend)} A[c,r]*v[c] --------
      {
        float acc=0.f;
        if (rv){
          const float* Ar = A + r;
          int nfull = (cend-cstart) >> 4;
          float b0[16], b1[16];
          if (nfull>0){
            #pragma unroll
            for (int u=0;u<16;++u) b0[u] = Ar[(size_t)(cstart+u)*256];
          }
          int t=0;
          for (; t+2<=nfull; t+=2){
            int cB = cstart+(t+1)*16;
            #pragma unroll
            for (int u=0;u<16;++u) b1[u] = Ar[(size_t)(cB+u)*256];
            int cA = cstart+t*16;
            #pragma unroll
            for (int u=0;u<16;++u) acc = fmaf(b0[u], v[cA+u], acc);
            if (t+2 < nfull){
              int cC = cstart+(t+2)*16;
              #pragma unroll
              for (int u=0;u<16;++u) b0[u] = Ar[(size_t)(cC+u)*256];
            }
            #pragma unroll
            for (int u=0;u<16;++u) acc = fmaf(b1[u], v[cB+u], acc);
          }
          if (t<nfull){
            int cA = cstart+t*16;
            #pragma unroll
            for (int u=0;u<16;++u) acc = fmaf(b0[u], v[cA+u], acc);
            ++t;
          }
          for (int c2=cstart+nfull*16; c2<cend; ++c2)
            acc = fmaf(Ar[(size_t)c2*256], v[c2], acc);
        }
        accbuf[half*256+rid] = acc;
      }
      __syncthreads();
      if (half==0 && rv) wv[r] = tau*(accbuf[rid] + accbuf[256+rid]);
      __syncthreads();
      float sd = (half==0 && rv)? v[r]*wv[r] : 0.f;
      float dotv = blk_reduce_sum512(sd, red, tid);
      float a2 = -0.5f*tau*dotv;
      if (half==0 && rv) wv[r] += a2*v[r];
      __syncthreads();
      // ---- rank-2 half: A[c,r] -= v[r]*wv[c] + wv[r]*v[c], c in half ------
      if (rv){
        float vr=v[r], wr=wv[r];
        float* Arw = A + r;
        int nfull = (cend-cstart) >> 4;
        float b0[16], b1[16];
        if (nfull>0){
          #pragma unroll
          for (int u=0;u<16;++u) b0[u] = Arw[(size_t)(cstart+u)*256];
        }
        int t=0;
        for (; t+2<=nfull; t+=2){
          int cB = cstart+(t+1)*16;
          #pragma unroll
          for (int u=0;u<16;++u) b1[u] = Arw[(size_t)(cB+u)*256];
          int cA = cstart+t*16;
          #pragma unroll
          for (int u=0;u<16;++u) b0[u] -= vr*wv[cA+u] + wr*v[cA+u];
          #pragma unroll
          for (int u=0;u<16;++u) Arw[(size_t)(cA+u)*256] = b0[u];
          if (t+2 < nfull){
            int cC = cstart+(t+2)*16;
            #pragma unroll
            for (int u=0;u<16;++u) b0[u] = Arw[(size_t)(cC+u)*256];
          }
          #pragma unroll
          for (int u=0;u<16;++u) b1[u] -= vr*wv[cB+u] + wr*v[cB+u];
          #pragma unroll
          for (int u=0;u<16;++u) Arw[(size_t)(cB+u)*256] = b1[u];
        }
        if (t<nfull){
          int cA = cstart+t*16;
          #pragma unroll
          for (int u=0;u<16;++u) b0[u] -= vr*wv[cA+u] + wr*v[cA+u];
          #pragma unroll
          for (int u=0;u<16;++u) Arw[(size_t)(cA+u)*256] = b0[u];
          ++t;
        }
        for (int c2=cstart+nfull*16; c2<cend; ++c2)
          Arw[(size_t)c2*256] -= vr*wv[c2] + wr*v[c2];
      }
      __syncthreads();
    }
    __syncthreads();
  }

  // ------------- copy trailing submatrix [PHB_I0..255]^2 to LDS ------------
  for (int idx=tid; idx<PHB_M*PHB_M; idx+=512){
    int cc = idx / PHB_M, rr = idx - cc*PHB_M;
    Asub[idx] = A[(size_t)(PHB_I0+cc)*256 + (PHB_I0+rr)];
  }
  __syncthreads();

  // ---------------- phase B: steps PHB_I0..254 in LDS ----------------------
  for (int i=PHB_I0;i<255;++i){
    int cb = (i - PHB_I0)*PHB_M;
    float alpha = Asub[cb + (i+1-PHB_I0)];
    float s=0.f;
    { int r=i+2+tid; if (r<256){ float a=Asub[cb + (r-PHB_I0)]; s=a*a; } }
    float xnorm2 = blk_reduce_sum512(s, red, tid);
    float tau=0.f, scale=0.f, beta=alpha;
    if (xnorm2 > 0.f){
      float r_ = sqrtf(alpha*alpha + xnorm2);
      beta = (alpha >= 0.f) ? -r_ : r_;
      tau = (beta - alpha)/beta;
      scale = 1.0f/(alpha - beta);
    }
    if (tid==0){ e_g[b*256+i] = beta; tau_g[b*256+i] = tau; }
    if (tau != 0.f){
      { int r=i+1+tid;
        if (r<256){
          float val = (r==i+1)?1.0f : Asub[cb+(r-PHB_I0)]*scale;
          Asub[cb+(r-PHB_I0)] = val;
          A[(size_t)i*256+r] = val;   // write-through: k_backtf reads this column
          v[r] = val;
        }
      }
      __syncthreads();
      int r = i+1+rid;
      bool rv = (r < 256);
      int ro = r - PHB_I0;
      int cmid = (i+1+256) >> 1;
      int cstart = (half==0)? (i+1) : cmid;
      int cend   = (half==0)? cmid  : 256;
      {
        float acc=0.f;
        if (rv){
          int nfull = (cend-cstart) >> 4;
          for (int t=0;t<nfull;++t){
            int cA = cstart + t*16;
            float av[16];
            #pragma unroll
            for (int u=0;u<16;++u) av[u] = Asub[(cA+u-PHB_I0)*PHB_M + ro];
            #pragma unroll
            for (int u=0;u<16;++u) acc = fmaf(av[u], v[cA+u], acc);
          }
          for (int c2=cstart+nfull*16;c2<cend;++c2)
            acc = fmaf(Asub[(c2-PHB_I0)*PHB_M+ro], v[c2], acc);
        }
        accbuf[half*256+rid] = acc;
      }
      __syncthreads();
      if (half==0 && rv) wv[r] = tau*(accbuf[rid] + accbuf[256+rid]);
      __syncthreads();
      float sd = (half==0 && rv)? v[r]*wv[r] : 0.f;
      float dotv = blk_reduce_sum512(sd, red, tid);
      float a2 = -0.5f*tau*dotv;
      if (half==0 && rv) wv[r] += a2*v[r];
      __syncthreads();
      if (rv){
        float vr=v[r], wr=wv[r];
        int nfull = (cend-cstart) >> 4;
        for (int t=0;t<nfull;++t){
          int cA=cstart+t*16;
          float av[16];
          #pragma unroll
          for (int u=0;u<16;++u) av[u] = Asub[(cA+u-PHB_I0)*PHB_M+ro];
          #pragma unroll
          for (int u=0;u<16;++u) av[u] -= vr*wv[cA+u] + wr*v[cA+u];
          #pragma unroll
          for (int u=0;u<16;++u) Asub[(cA+u-PHB_I0)*PHB_M+ro] = av[u];
        }
        for (int c2=cstart+nfull*16;c2<cend;++c2)
          Asub[(c2-PHB_I0)*PHB_M+ro] -= vr*wv[c2] + wr*v[c2];
      }
      __syncthreads();
    }
    __syncthreads();
  }
  if (tid < 256){
    int r = tid;
    float dv = (r >= PHB_I0)? Asub[(r-PHB_I0)*PHB_M + (r-PHB_I0)] : A[(size_t)r*256+r];
    d_g[b*256+r] = dv;
  }
}

// ------------------- leaves: lockstep wave-parallel Jacobi -------------------
__global__ __launch_bounds__(256) void k_leaf(const float* __restrict__ d_g,
                                              const float* __restrict__ e_g,
                                              float* __restrict__ Qg,
                                              double* __restrict__ Dw_g,
                                              double* __restrict__ emod_g){
  int b = blockIdx.x, tid = threadIdx.x;
  float* Q = Qg + (size_t)b*65536;
  double* Dw = Dw_g + (size_t)b*256;
  __shared__ double As[16*257];
  __shared__ float  Vt[16*257];
  __shared__ double dms[256];
  __shared__ double emod[256];
  __shared__ float redf[256];

  float dv = d_g[b*256+tid];
  float ev = (tid<255)? e_g[b*256+tid] : 0.f;
  redf[tid] = fmaxf(fabsf(dv), fabsf(ev)); __syncthreads();
  for(int o=128;o>0;o>>=1){ if(tid<o) redf[tid]=fmaxf(redf[tid],redf[tid+o]); __syncthreads(); }
  double sigma = (double)redf[0];
  if (!(sigma > 0.0)) sigma = 1.0;
  double dmod = (double)dv;
  if ((tid & 15)==15 && tid<255) dmod -= fabs((double)e_g[b*256+tid]);
  if ((tid & 15)==0  && tid>0)   dmod -= fabs((double)e_g[b*256+tid-1]);
  dmod /= sigma;
  double em = (tid<255)? ((double)ev)/sigma : 0.0;
  dms[tid] = dmod;  emod[tid] = em;
  emod_g[b*256+tid] = em;
  __syncthreads();

  int l16 = tid & ~15, j = tid & 15;
  for (int r=0;r<16;++r){
    double av = 0.0;
    if (r==j)        av = dms[l16+j];
    else if (r==j-1) av = emod[l16+j-1];
    else if (r==j+1) av = emod[l16+j];
    As[r*257+tid] = av;
    Vt[r*257+tid] = (r==j)? 1.f : 0.f;
  }
  __syncthreads();

  for (int sweep=0; sweep<14; ++sweep){
    for (int p=0;p<15;++p){
      for (int q=p+1;q<16;++q){
        double app = As[p*257 + l16+p];
        double aqq = As[q*257 + l16+q];
        double apq = As[p*257 + l16+q];
        bool rot = (fabs(apq) > 1e-18);
        double c, s;
        if (rot){
          double theta = (aqq - app)/(2.0*apq);
          double t = 1.0/(fabs(theta)+sqrt(1.0+theta*theta));
          if (theta < 0.0) t = -t;
          c = 1.0/sqrt(1.0+t*t); s = t*c;
        } else { c = 1.0; s = 0.0; }
        double apj = As[p*257 + tid];
        double aqj = As[q*257 + tid];
        double npj = c*apj - s*aqj;
        double nqj = s*apj + c*aqj;
        if (rot && j==p){ npj = c*c*app - 2.0*c*s*apq + s*s*aqq; nqj = 0.0; }
        if (rot && j==q){ npj = 0.0; nqj = s*s*app + 2.0*c*s*apq + c*c*aqq; }
        As[p*257 + tid] = npj;
        As[q*257 + tid] = nqj;
        As[j*257 + l16+p] = npj;
        As[j*257 + l16+q] = nqj;
        float vp = Vt[p*257 + tid], vq = Vt[q*257 + tid];
        Vt[p*257 + tid] = (float)(c*(double)vp - s*(double)vq);
        Vt[q*257 + tid] = (float)(s*(double)vp + c*(double)vq);
      }
    }
  }
  __syncthreads();
  double myval = As[j*257 + l16+j];
  int rank = 0;
  for (int k=0;k<16;++k){
    double vk = As[k*257 + l16+k];
    if (vk < myval || (vk==myval && k<j)) ++rank;
  }
  Dw[l16+rank] = myval;
  for (int r=0;r<16;++r)
    Q[(size_t)(l16+r)*256 + (l16+rank)] = Vt[j*257 + l16+r];
}

// ---------------- merge solve (slaed2 + secular), one block per merge --------
struct DCMerge {
  double z_[256], dsv[256], ds2[256], zs2[256];
  double dl_[256], zl_[256], taus[256], ztil[256], normk[256], evo[256];
  double rotcs[256][2];
  int    cs2[256], colx[256], non_[256], defl_[256], anch[256], osrc[256], otyp[256];
  int    roti[256][2];
};

// Global state layout, slot = b*8 + mrg, each array stride 256 per slot.
__global__ __launch_bounds__(256) void k_msolve(int lev,
                                                const double* __restrict__ emod_g,
                                                float* __restrict__ Qsrc,   // rotated in place
                                                double* __restrict__ Dw_g,
                                                double* __restrict__ Sdl,
                                                double* __restrict__ Sztil,
                                                double* __restrict__ Staus,
                                                double* __restrict__ Snk,
                                                int* __restrict__ Scolx,
                                                int* __restrict__ Sanch,
                                                int* __restrict__ Sotyp,
                                                int* __restrict__ Sosrc,
                                                int* __restrict__ SK){
  int mrg = blockIdx.x, b = blockIdx.y, tid = threadIdx.x;
  float* Q  = Qsrc + (size_t)b*65536;
  double* Dw = Dw_g + (size_t)b*256;
  int slot = b*8 + mrg;
  __shared__ DCMerge mg;
  __shared__ int bci[4];

  int ssz = 16<<lev, nm = ssz<<1;
  int base = mrg*nm;
  double rho0 = emod_g[b*256 + base+ssz-1];
  if (tid < nm){
    float zf = (tid < ssz) ? Q[(size_t)(base+ssz-1)*256 + base + tid]
                           : Q[(size_t)(base+ssz)*256   + base + tid];
    double zz = (double)zf;
    if (rho0 < 0.0 && tid >= ssz) zz = -zz;
    mg.z_[tid] = zz * 0.70710678118654752440;
    mg.dsv[tid] = Dw[base+tid];
  }
  __syncthreads();
  double rho = fabs(2.0*rho0);
  if (tid==0){
    int i1=0, i2=ssz, o=0;
    while (i1<ssz || i2<nm){
      bool take1;
      if (i1>=ssz) take1=false; else if (i2>=nm) take1=true;
      else take1 = (mg.dsv[i1] <= mg.dsv[i2]);
      int src = take1? i1++ : i2++;
      mg.ds2[o]=mg.dsv[src]; mg.zs2[o]=mg.z_[src]; mg.cs2[o]=src; ++o;
    }
  }
  __syncthreads();
  mg.taus[tid] = (tid<nm)? fabs(mg.zs2[tid]) : 0.0; __syncthreads();
  for(int o2=128;o2>0;o2>>=1){ if(tid<o2) mg.taus[tid]=fmax(mg.taus[tid],mg.taus[tid+o2]); __syncthreads(); }
  double zmax = mg.taus[0]; __syncthreads();
  mg.taus[tid] = (tid<nm)? fabs(mg.ds2[tid]) : 0.0; __syncthreads();
  for(int o2=128;o2>0;o2>>=1){ if(tid<o2) mg.taus[tid]=fmax(mg.taus[tid],mg.taus[tid+o2]); __syncthreads(); }
  double dmax = mg.taus[0]; __syncthreads();
  double tol = 8.0*LAPACK_EPS32*fmax(dmax, zmax);
  if (tid==0){
    int K=0, nd=0, nrot=0, pj=-1;
    for (int j=0;j<nm;++j){
      if (rho*fabs(mg.zs2[j]) <= tol){ mg.defl_[nd++]=j; continue; }
      if (pj>=0){
        double sg=mg.zs2[pj], cg=mg.zs2[j];
        double tg=mg.ds2[j]-mg.ds2[pj];
        double taug=sqrt(cg*cg+sg*sg);
        double cn, sn;
        if (taug > 0.0){ cn=cg/taug; sn=-sg/taug; } else { cn=1.0; sn=0.0; }
        if (fabs(tg*cn*sn) <= tol){
          mg.zs2[j]=taug; mg.zs2[pj]=0.0;
          mg.roti[nrot][0]=mg.cs2[pj]; mg.roti[nrot][1]=mg.cs2[j];
          mg.rotcs[nrot][0]=cn; mg.rotcs[nrot][1]=sn; ++nrot;
          double t2 = mg.ds2[pj]*cn*cn + mg.ds2[j]*sn*sn;
          mg.ds2[j] = mg.ds2[pj]*sn*sn + mg.ds2[j]*cn*cn;
          mg.ds2[pj] = t2;
          mg.defl_[nd++]=pj;
          pj=j;
        } else { mg.non_[K++]=pj; pj=j; }
      } else pj=j;
    }
    if (pj>=0) mg.non_[K++]=pj;
    bci[0]=K; bci[1]=nd; bci[2]=nrot;
  }
  __syncthreads();
  int K=bci[0], nd=bci[1], nrot=bci[2];
  // Givens rotations on src Q columns (in order)
  for (int r2=0;r2<nrot;++r2){
    int ca = base + mg.roti[r2][0], cb2 = base + mg.roti[r2][1];
    double cn = mg.rotcs[r2][0], sn = mg.rotcs[r2][1];
    if (tid < nm){
      int row = base+tid;
      float xv = Q[(size_t)row*256+ca], yv = Q[(size_t)row*256+cb2];
      Q[(size_t)row*256+ca]  = (float)(cn*(double)xv + sn*(double)yv);
      Q[(size_t)row*256+cb2] = (float)(cn*(double)yv - sn*(double)xv);
    }
    __syncthreads();
  }
  if (tid<K){
    mg.dl_[tid]=mg.ds2[mg.non_[tid]];
    mg.zl_[tid]=mg.zs2[mg.non_[tid]];
    mg.colx[tid]=mg.cs2[mg.non_[tid]];
  }
  __syncthreads();
  mg.taus[tid] = (tid<K)? mg.zl_[tid]*mg.zl_[tid] : 0.0; __syncthreads();
  for(int o2=128;o2>0;o2>>=1){ if(tid<o2) mg.taus[tid]+=mg.taus[tid+o2]; __syncthreads(); }
  double zsum2 = mg.taus[0]; __syncthreads();
  if (tid<K){
    int j=tid;
    double left=mg.dl_[j];
    double right=(j<K-1)? mg.dl_[j+1] : (mg.dl_[K-1] + rho*zsum2);
    double mid=0.5*(left+right);
    double fm=1.0;
    for (int i3=0;i3<K;++i3){
      double del=mg.dl_[i3]-mid;
      fm += rho*mg.zl_[i3]*mg.zl_[i3]/del;
    }
    int a; double lo, hi;
    if (j==K-1){
      a=K-1;
      if (fm<=0.0){ lo=mid-left; hi=right-left; } else { lo=0.0; hi=mid-left; }
    } else if (fm<=0.0){ a=j+1; lo=mid-mg.dl_[j+1]; hi=0.0; }
    else { a=j; lo=0.0; hi=mid-left; }
    double da2=mg.dl_[a];
    double t;
    if (hi > lo){
      t=0.5*(lo+hi);
    } else {
      t = (a==j)? 1e-300 : -1e-300;
      lo = fmin(lo, t); hi = fmax(hi, t);
    }
    for (int it=0; it<100; ++it){
      double gg=1.0, dg=0.0;
      for (int i3=0;i3<K;++i3){
        double del=(mg.dl_[i3]-da2)-t;
        double q=mg.zl_[i3]/del;
        gg += rho*mg.zl_[i3]*q;
        dg += rho*q*q;
      }
      if (gg<0.0) lo=t; else hi=t;
      double tn = t - gg/dg;
      if (!isfinite(tn) || !(tn>lo && tn<hi)) tn=0.5*(lo+hi);
      if (tn == 0.0) tn = (t!=0.0)? t*0.5 : ((a==j)?1e-300:-1e-300);
      double dstep=fabs(tn-t);
      t=tn;
      if (dstep <= 1e-15*(fabs(t)+1e-30)) break;
      if ((hi-lo) <= 1e-15*(fabs(da2)+fabs(t)+1e-30)) break;
    }
    if (t == 0.0 || !isfinite(t)) t = (a==j)? 1e-300 : -1e-300;
    mg.taus[j]=t; mg.anch[j]=a;
  }
  __syncthreads();
  if (tid<K){
    int i3=tid; double acc=0.0; double di=mg.dl_[i3];
    for (int j=0;j<K;++j){
      double lmd = (mg.dl_[mg.anch[j]] - di) + mg.taus[j];
      acc += safelog(lmd);
      if (j!=i3) acc -= safelog(mg.dl_[j]-di);
    }
    double mag = exp(0.5*acc);
    if (!isfinite(mag)) mag = 0.0;
    mg.ztil[i3] = (mg.zl_[i3] >= 0.0)? mag : -mag;
  }
  __syncthreads();
  if (tid<K){
    int j=tid; double da2=mg.dl_[mg.anch[j]]; double tj=mg.taus[j];
    double nr=0.0;
    for (int i3=0;i3<K;++i3){
      double del=(mg.dl_[i3]-da2)-tj;
      if (del == 0.0) del = (tj>=0.0)? -1e-300 : 1e-300;
      double sv=mg.ztil[i3]/del;
      nr += sv*sv;
    }
    if (!(nr > 0.0) || !isfinite(nr)) nr = 1.0;
    mg.normk[j]=sqrt(nr);
  }
  __syncthreads();
  // output ordering
  if (tid==0){
    for (int a2=1;a2<nd;++a2){
      int key=mg.defl_[a2]; double kv=mg.ds2[key]; int b2=a2-1;
      while (b2>=0 && mg.ds2[mg.defl_[b2]] > kv){ mg.defl_[b2+1]=mg.defl_[b2]; --b2; }
      mg.defl_[b2+1]=key;
    }
    int i1=0,i2=0,o=0;
    while (i1<K || i2<nd){
      double v1 = (i1<K)? (mg.dl_[mg.anch[i1]]+mg.taus[i1]) : 0.0;
      double v2 = (i2<nd)? mg.ds2[mg.defl_[i2]] : 0.0;
      bool take1;
      if (i1>=K) take1=false; else if (i2>=nd) take1=true; else take1 = (v1 <= v2);
      if (take1){ mg.otyp[o]=0; mg.osrc[o]=i1; mg.evo[o]=v1; ++i1; }
      else { mg.otyp[o]=1; mg.osrc[o]=mg.cs2[mg.defl_[i2]]; mg.evo[o]=v2; ++i2; }
      ++o;
    }
  }
  __syncthreads();
  if (tid<nm) Dw[base+tid]=mg.evo[tid];
  // write state
  size_t so = (size_t)slot*256;
  if (tid<K){
    Sdl[so+tid]=mg.dl_[tid]; Sztil[so+tid]=mg.ztil[tid];
    Staus[so+tid]=mg.taus[tid]; Snk[so+tid]=mg.normk[tid];
    Scolx[so+tid]=mg.colx[tid]; Sanch[so+tid]=mg.anch[tid];
  }
  if (tid<nm){ Sotyp[so+tid]=mg.otyp[tid]; Sosrc[so+tid]=mg.osrc[tid]; }
  if (tid==0) SK[slot]=K;
}

// ---------------- merge assemble: Qdst[:,p] = Qsrc_sub @ svf  ----------------
// grid: (nm/16 col-tiles, nmerge, 16 batches); block 256.
__global__ __launch_bounds__(256) void k_mvec(int lev,
                                              const float* __restrict__ Qsrc_g,
                                              float* __restrict__ Qdst_g,
                                              const double* __restrict__ Sdl,
                                              const double* __restrict__ Sztil,
                                              const double* __restrict__ Staus,
                                              const double* __restrict__ Snk,
                                              const int* __restrict__ Scolx,
                                              const int* __restrict__ Sanch,
                                              const int* __restrict__ Sotyp,
                                              const int* __restrict__ Sosrc,
                                              const int* __restrict__ SK){
  int t = blockIdx.x, mrg = blockIdx.y, b = blockIdx.z, tid = threadIdx.x;
  const float* Q = Qsrc_g + (size_t)b*65536;
  float* Qd = Qdst_g + (size_t)b*65536;
  int slot = b*8 + mrg;
  size_t so = (size_t)slot*256;
  int ssz = 16<<lev, nm = ssz<<1;
  int base = mrg*nm;
  int p0 = t*16;
  int K = SK[slot];

  __shared__ float svf[256*16];      // [i3][c], stride 16: compute idx==tid -> conflict-free
  __shared__ double cda[16], ctj[16];
  __shared__ float cnk[16];
  __shared__ int ctyp[16], csrc[16];

  if (tid < 16){
    int p = p0 + tid;
    int typ = Sotyp[so+p], src = Sosrc[so+p];
    ctyp[tid]=typ; csrc[tid]=src;
    if (typ==0){
      int j = src;
      cda[tid] = Sdl[so + Sanch[so+j] - 0 + 0];    // placeholder; fixed below
    }
  }
  __syncthreads();
  // fix cda/ctj/cnk properly (need anch lookup)
  if (tid < 16){
    int p = p0 + tid;
    if (ctyp[tid]==0){
      int j = csrc[tid];
      int a = Sanch[so+j];
      cda[tid] = Sdl[so+a];
      ctj[tid] = Staus[so+j];
      cnk[tid] = (float)Snk[so+j];
    } else { cda[tid]=0.0; ctj[tid]=1.0; cnk[tid]=1.f; }
  }
  __syncthreads();
  // build svf tile
  for (int idx = tid; idx < K*16; idx += 256){
    int i3 = idx >> 4, c = idx & 15;
    float sv = 0.f;
    if (ctyp[c]==0){
      double del = (Sdl[so+i3] - cda[c]) - ctj[c];
      if (del == 0.0) del = (ctj[c]>=0.0)? -1e-300 : 1e-300;
      sv = (float)( Sztil[so+i3]/del / (double)cnk[c] );
      if (!isfinite(sv)) sv = 0.f;
    }
    svf[i3*16 + c] = sv;
  }
  __syncthreads();

  // rows: one thread per row (nm <= 256)
  if (tid < nm){
    int row = base + tid;
    const float* Qr = Q + (size_t)row*256 + base;
    float acc[16];
    #pragma unroll
    for (int c=0;c<16;++c) acc[c]=0.f;
    for (int i3=0;i3<K;++i3){
      float qv = Qr[Scolx[so+i3]];
      #pragma unroll
      for (int c=0;c<16;++c) acc[c] = fmaf(qv, svf[i3*16+c], acc[c]);
    }
    #pragma unroll
    for (int c=0;c<16;++c){
      float v = acc[c];
      if (ctyp[c]==1) v = Qr[csrc[c]];
      if (!isfinite(v)) v = 0.f;
      Qd[(size_t)row*256 + base + p0 + c] = v;
    }
  }
}

// --------------- back-transform: U16 = H_1...H_255 * Vtri[:,240:256] ---------
// 512 threads (measured win in R14/R15): 32 row-groups x 8 rows.
__global__ __launch_bounds__(512,1) void k_backtf(const float* __restrict__ Ag,
                                                  const float* __restrict__ tau_g,
                                                  const float* __restrict__ Qg,
                                                  float* __restrict__ w16g){
  int b=blockIdx.x, tid=threadIdx.x;
  const float* A=Ag+(size_t)b*65536;
  const float* Q=Qg+(size_t)b*65536;
  __shared__ float U[256][17];
  __shared__ float pd[32][17];
  __shared__ float dk[16];
  int k=tid&15, rg=tid>>4;   // rg in 0..31
  for (int r=rg;r<256;r+=32) U[r][k]=Q[(size_t)r*256+240+k];
  __syncthreads();
  for (int i=254;i>=0;--i){
    float tau=tau_g[b*256+i];
    if (tau!=0.f){
      int r0 = i+1+rg;
      float ar[8];
      #pragma unroll
      for (int u=0;u<8;++u){
        int r = r0 + u*32;
        ar[u] = (r<256)? A[(size_t)i*256+r] : 0.f;
      }
      float uv[8];
      #pragma unroll
      for (int u=0;u<8;++u){
        int r = r0 + u*32;
        uv[u] = (r<256)? U[r][k] : 0.f;
      }
      float s=0.f;
      #pragma unroll
      for (int u=0;u<8;++u){
        int r = r0 + u*32;
        if (r<256) s += ar[u]*uv[u];
      }
      pd[rg][k]=s;
      __syncthreads();
      if (tid<16){
        float acc=0.f;
        #pragma unroll
        for (int gg=0; gg<32; ++gg) acc+=pd[gg][tid];
        dk[tid]=tau*acc;
      }
      __syncthreads();
      float dkk = dk[k];
      #pragma unroll
      for (int u=0;u<8;++u){
        int r = r0 + u*32;
        if (r<256) U[r][k] -= dkk*ar[u];
      }
      __syncthreads();
    }
  }
  for (int c2=rg;c2<256;c2+=32){
    float uv = U[c2][k];
    if (!isfinite(uv)) uv = 0.f;
    w16g[((size_t)b*16+k)*256+c2]=uv;
  }
}

// ---------------- fused scores + softmax + y (replaces k_score/k_y) ----------
// Each thread owns column n of g: reads all 256 channels (score, identical
// FP sequence to old k_score), softmaxes, then writes y over the same column
// (identical FP sequence to old k_y). z never materialized. No cross-thread
// sharing of g columns -> race-free in-place. Bit-exact (R16/R17 measured).
__global__ __launch_bounds__(256) void k_scy(float* __restrict__ g,
                                             const float* __restrict__ w16){
  __shared__ __attribute__((aligned(16))) float ws[256][16];   // [c2][k2]
  int nt=blockIdx.x, b=blockIdx.y, tid=threadIdx.x;
  for (int i=tid;i<4096;i+=256) ws[i&255][i>>8]=w16[(size_t)b*4096+i];
  __syncthreads();
  int n=nt*256+tid;
  float* gp=g+(size_t)b*NC*NSP+n;
  float acc[16];
  #pragma unroll
  for(int k2=0;k2<16;++k2) acc[k2]=0.f;
  for (int c2=0;c2<256;++c2){
    float gv=gp[(size_t)c2*NSP];
    float4 wa=*(const float4*)&ws[c2][0];
    float4 wb=*(const float4*)&ws[c2][4];
    float4 wc=*(const float4*)&ws[c2][8];
    float4 wd=*(const float4*)&ws[c2][12];
    acc[0] =fmaf(wa.x,gv,acc[0]);  acc[1] =fmaf(wa.y,gv,acc[1]);
    acc[2] =fmaf(wa.z,gv,acc[2]);  acc[3] =fmaf(wa.w,gv,acc[3]);
    acc[4] =fmaf(wb.x,gv,acc[4]);  acc[5] =fmaf(wb.y,gv,acc[5]);
    acc[6] =fmaf(wb.z,gv,acc[6]);  acc[7] =fmaf(wb.w,gv,acc[7]);
    acc[8] =fmaf(wc.x,gv,acc[8]);  acc[9] =fmaf(wc.y,gv,acc[9]);
    acc[10]=fmaf(wc.z,gv,acc[10]); acc[11]=fmaf(wc.w,gv,acc[11]);
    acc[12]=fmaf(wd.x,gv,acc[12]); acc[13]=fmaf(wd.y,gv,acc[13]);
    acc[14]=fmaf(wd.z,gv,acc[14]); acc[15]=fmaf(wd.w,gv,acc[15]);
  }
  float mx=-1e30f;
  #pragma unroll
  for(int k2=0;k2<16;++k2){ acc[k2]*=3.0f; mx=fmaxf(mx,acc[k2]); }
  float sum=0.f;
  #pragma unroll
  for(int k2=0;k2<16;++k2){ acc[k2]=expf(acc[k2]-mx); sum+=acc[k2]; }
  float inv=1.0f/sum;
  #pragma unroll
  for(int k2=0;k2<16;++k2) acc[k2]*=inv;     // z values, identical to old path
  for (int c2=0;c2<256;++c2){
    float4 wa=*(const float4*)&ws[c2][0];
    float4 wb=*(const float4*)&ws[c2][4];
    float4 wc=*(const float4*)&ws[c2][8];
    float4 wd=*(const float4*)&ws[c2][12];
    float a=0.f;
    a=fmaf(wa.x,acc[0],a);  a=fmaf(wa.y,acc[1],a);
    a=fmaf(wa.z,acc[2],a);  a=fmaf(wa.w,acc[3],a);
    a=fmaf(wb.x,acc[4],a);  a=fmaf(wb.y,acc[5],a);
    a=fmaf(wb.z,acc[6],a);  a=fmaf(wb.w,acc[7],a);
    a=fmaf(wc.x,acc[8],a);  a=fmaf(wc.y,acc[9],a);
    a=fmaf(wc.z,acc[10],a); a=fmaf(wc.w,acc[11],a);
    a=fmaf(wd.x,acc[12],a); a=fmaf(wd.y,acc[13],a);
    a=fmaf(wd.z,acc[14],a); a=fmaf(wd.w,acc[15],a);
    gp[(size_t)c2*NSP]=a;
  }
}

// ------------------------- conv2(3x3) + BN + residual ------------------------
// Round-5 form VERBATIM (1806us known-good): cc-outer, dd fully unrolled,
// unpadded wt[16][8][9], scalar broadcast reads, 1 output/thread, ht=16.
// CLOSED: three restructure attempts (R11/R12/R16) all regressed.
__global__ __launch_bounds__(256) void k_conv2(const float* __restrict__ y,
                                               const void* __restrict__ w2v,
                                               const void* __restrict__ xv_,
                                               const void* __restrict__ gmv,
                                               const void* __restrict__ btv,
                                               const void* __restrict__ muv,
                                               const void* __restrict__ vrv,
                                               const int* __restrict__ flags,
                                               void* __restrict__ outv){
  __shared__ float yt[8][6][66];
  __shared__ float wt[16][8][9];
  int ht=blockIdx.x, ct=blockIdx.y, b=blockIdx.z, tid=threadIdx.x;
  int hl=tid>>6, wl=tid&63;
  int h=ht*4+hl;
  int c0=ct*16;
  int isf = flags[0];
  float acc[16];
  #pragma unroll
  for(int i=0;i<16;++i) acc[i]=0.f;
  const float* yb = y + (size_t)b*NC*NSP;
  for (int d0=0; d0<256; d0+=8){
    for (int idx=tid; idx<8*6*64; idx+=256){
      int dd=idx/384; int rem=idx-dd*384; int rr=rem>>6; int cc2=rem&63;
      int hg=ht*4-1+rr;
      float v = (hg>=0 && hg<64)? yb[(size_t)(d0+dd)*NSP + hg*64 + cc2] : 0.f;
      yt[dd][rr][cc2+1]=v;
    }
    if (tid<48){ int dd=tid/6, rr=tid-dd*6; yt[dd][rr][0]=0.f; yt[dd][rr][65]=0.f; }
    if (isf){
      const float* w2 = (const float*)w2v;
      for (int idx=tid; idx<16*8*9; idx+=256){
        int cc=idx/72; int rem=idx-cc*72; int dd=rem/9; int kk=rem-dd*9;
        wt[cc][dd][kk]=w2[ ((size_t)(c0+cc)*256 + d0+dd)*9 + kk ];
      }
    } else {
      const bf16* w2 = (const bf16*)w2v;
      for (int idx=tid; idx<16*8*9; idx+=256){
        int cc=idx/72; int rem=idx-cc*72; int dd=rem/9; int kk=rem-dd*9;
        wt[cc][dd][kk]=b2f(w2[ ((size_t)(c0+cc)*256 + d0+dd)*9 + kk ]);
      }
    }
    __syncthreads();
    for (int cc=0; cc<16; ++cc){
      float a=acc[cc];
      #pragma unroll
      for (int dd=0; dd<8; ++dd){
        const float* wp=wt[cc][dd];
        a = fmaf(wp[0], yt[dd][hl+0][wl+0], a);
        a = fmaf(wp[1], yt[dd][hl+0][wl+1], a);
        a = fmaf(wp[2], yt[dd][hl+0][wl+2], a);
        a = fmaf(wp[3], yt[dd][hl+1][wl+0], a);
        a = fmaf(wp[4], yt[dd][hl+1][wl+1], a);
        a = fmaf(wp[5], yt[dd][hl+1][wl+2], a);
        a = fmaf(wp[6], yt[dd][hl+2][wl+0], a);
        a = fmaf(wp[7], yt[dd][hl+2][wl+1], a);
        a = fmaf(wp[8], yt[dd][hl+2][wl+2], a);
      }
      acc[cc]=a;
    }
    __syncthreads();
  }
  size_t nidx=(size_t)h*64+wl;
  for (int cc=0;cc<16;++cc){
    int c=c0+cc;
    float gmf, btf, muf, vrf, xvv;
    size_t oi = ((size_t)b*NC+c)*NSP + nidx;
    if (isf){
      gmf=((const float*)gmv)[c]; btf=((const float*)btv)[c];
      muf=((const float*)muv)[c]; vrf=((const float*)vrv)[c];
      xvv=((const float*)xv_)[oi];
    } else {
      gmf=b2f(((const bf16*)gmv)[c]); btf=b2f(((const bf16*)btv)[c]);
      muf=b2f(((const bf16*)muv)[c]); vrf=b2f(((const bf16*)vrv)[c]);
      xvv=b2f(((const bf16*)xv_)[oi]);
    }
    float inv = gmf * rsqrtf(vrf + 1e-5f);
    float shift = btf - muf*inv;
    float val = xvv + acc[cc]*inv + shift;
    if (isf) ((float*)outv)[oi] = val;
    else     ((bf16*)outv)[oi] = __float2bfloat16(val);
  }
}

// ---------------------------------------------------------------------------
extern "C" void kernel_launch(void* const* d_in, const int* in_sizes, int n_in,
                              void* d_out, int out_size, void* d_ws, size_t ws_size,
                              hipStream_t stream) {
  const void* x   = d_in[0];
  const void* w1  = d_in[1];
  // d_in[2] = conv1_b: constant over spatial -> cancelled by centering; unused.
  const void* w2  = d_in[3];
  const void* gmm = d_in[4];
  const void* bet = d_in[5];
  const void* mu  = d_in[6];
  const void* var = d_in[7];

  float* g    = (float*)d_ws;                      // 16*256*4096 (later reused as y)
  float* A    = g   + (size_t)NB*NC*NSP;
  float* Qa   = A   + (size_t)NB*NC*NC;
  float* Qb   = Qa  + (size_t)NB*NC*NC;
  float* w16  = Qb  + (size_t)NB*NC*NC;
  float* zb   = w16 + (size_t)NB*16*NC;            // unused since R16 fusion
  float* e_g  = zb  + (size_t)NB*16*NSP;
  float* tau_g= e_g + (size_t)NB*NC;
  float* d_g  = tau_g + (size_t)NB*NC;
  double* Dw  = (double*)(d_g + (size_t)NB*NC);
  double* emod_g = Dw + (size_t)NB*NC;
  double* Sdl   = emod_g + (size_t)NB*NC;
  double* Sztil = Sdl   + (size_t)128*256;
  double* Staus = Sztil + (size_t)128*256;
  double* Snk   = Staus + (size_t)128*256;
  int* Scolx = (int*)(Snk + (size_t)128*256);
  int* Sanch = Scolx + (size_t)128*256;
  int* Sotyp = Sanch + (size_t)128*256;
  int* Sosrc = Sotyp + (size_t)128*256;
  int* SK    = Sosrc + (size_t)128*256;
  int* flags = SK + 256;
  size_t needed = (size_t)((char*)(flags + 16) - (char*)d_ws);
  if (ws_size < needed) return;

  hipMemsetAsync(Qa, 0, (size_t)NB*NC*NC*2*sizeof(float), stream);  // Qa+Qb contiguous
  k_detect<<<dim3(1),256,0,stream>>>((const unsigned short*)x, flags);
  k_conv1 <<<dim3(16,16,16),256,0,stream>>>(x, w1, flags, g);
  k_center<<<dim3(NB*NC),256,0,stream>>>(g);
  k_cmat  <<<dim3(4,8,16),256,0,stream>>>(g, A);
  k_sytd2 <<<dim3(16),512,0,stream>>>(A, e_g, tau_g, d_g);
  k_leaf  <<<dim3(16),256,0,stream>>>(d_g, e_g, Qa, Dw, emod_g);
  // lev0: Qa -> Qb
  k_msolve<<<dim3(8,16),256,0,stream>>>(0, emod_g, Qa, Dw, Sdl,Sztil,Staus,Snk,Scolx,Sanch,Sotyp,Sosrc,SK);
  k_mvec  <<<dim3(2,8,16),256,0,stream>>>(0, Qa, Qb, Sdl,Sztil,Staus,Snk,Scolx,Sanch,Sotyp,Sosrc,SK);
  // lev1: Qb -> Qa
  k_msolve<<<dim3(4,16),256,0,stream>>>(1, emod_g, Qb, Dw, Sdl,Sztil,Staus,Snk,Scolx,Sanch,Sotyp,Sosrc,SK);
  k_mvec  <<<dim3(4,4,16),256,0,stream>>>(1, Qb, Qa, Sdl,Sztil,Staus,Snk,Scolx,Sanch,Sotyp,Sosrc,SK);
  // lev2: Qa -> Qb
  k_msolve<<<dim3(2,16),256,0,stream>>>(2, emod_g, Qa, Dw, Sdl,Sztil,Staus,Snk,Scolx,Sanch,Sotyp,Sosrc,SK);
  k_mvec  <<<dim3(8,2,16),256,0,stream>>>(2, Qa, Qb, Sdl,Sztil,Staus,Snk,Scolx,Sanch,Sotyp,Sosrc,SK);
  // lev3: Qb -> Qa
  k_msolve<<<dim3(1,16),256,0,stream>>>(3, emod_g, Qb, Dw, Sdl,Sztil,Staus,Snk,Scolx,Sanch,Sotyp,Sosrc,SK);
  k_mvec  <<<dim3(16,1,16),256,0,stream>>>(3, Qb, Qa, Sdl,Sztil,Staus,Snk,Scolx,Sanch,Sotyp,Sosrc,SK);
  k_backtf<<<dim3(16),512,0,stream>>>(A, tau_g, Qa, w16);
  k_scy   <<<dim3(16,16),256,0,stream>>>(g, w16);       // fused score+softmax+y (in-place)
  k_conv2 <<<dim3(16,16,16),256,0,stream>>>(g, w2, x, gmm, bet, mu, var, flags, d_out);
}